// Round 7
// baseline (448.411 us; speedup 1.0000x reference)
//
#include <hip/hip_runtime.h>
#include <math.h>

#define B_   2
#define T_   2048
#define DIM_ 2048
#define H_   16

typedef __attribute__((ext_vector_type(8))) _Float16 half8;
typedef __attribute__((ext_vector_type(4))) _Float16 half4;
typedef __attribute__((ext_vector_type(4))) float f32x4;

__device__ __forceinline__ float sigmoidf_(float x) { return 1.0f / (1.0f + __expf(-x)); }

__device__ __forceinline__ void gload16(const _Float16* g, _Float16* l) {
    __builtin_amdgcn_global_load_lds((const __attribute__((address_space(1))) void*)g,
                                     (__attribute__((address_space(3))) void*)l, 16, 0, 0);
}

#define VMW(n) asm volatile("s_waitcnt vmcnt(" #n ")" ::: "memory")

// ---------------------------------------------------------------------------
// prep: z<5 -> weight transpose W[K][N] f32 -> Wt[N][K] f16; z==5 -> x cvt.
// ---------------------------------------------------------------------------
__global__ __launch_bounds__(256) void prep(const float* __restrict__ W0,
                                            const float* __restrict__ W1,
                                            const float* __restrict__ W2,
                                            const float* __restrict__ W3,
                                            const float* __restrict__ W4,
                                            _Float16* __restrict__ wbase,
                                            const float* __restrict__ x,
                                            _Float16* __restrict__ xh)
{
    const int z = blockIdx.z;
    if (z == 5) {   // cvt: 1024 blocks x 32 elems/thread
        size_t blk = ((size_t)blockIdx.y * 32 + blockIdx.x) * 8192;
#pragma unroll
        for (int j = 0; j < 4; ++j) {
            size_t i = blk + (size_t)j * 2048 + (size_t)threadIdx.x * 8;
            float4 a = *(const float4*)(x + i);
            float4 b = *(const float4*)(x + i + 4);
            half8 h;
            h[0] = (_Float16)a.x; h[1] = (_Float16)a.y; h[2] = (_Float16)a.z; h[3] = (_Float16)a.w;
            h[4] = (_Float16)b.x; h[5] = (_Float16)b.y; h[6] = (_Float16)b.z; h[7] = (_Float16)b.w;
            *(half8*)(xh + i) = h;
        }
        return;
    }
    __shared__ float t[64][65];
    const float* W = z == 0 ? W0 : z == 1 ? W1 : z == 2 ? W2 : z == 3 ? W3 : W4;
    _Float16* Wt = wbase + (size_t)z * DIM_ * DIM_;
    const int c = threadIdx.x & 63;
    const int r0 = threadIdx.x >> 6;
    const int n0 = blockIdx.x * 64, k0 = blockIdx.y * 64;
#pragma unroll
    for (int i = 0; i < 16; ++i) {
        int r = i * 4 + r0;
        t[r][c] = W[(size_t)(k0 + r) * DIM_ + n0 + c];
    }
    __syncthreads();
#pragma unroll
    for (int i = 0; i < 16; ++i) {
        int r = i * 4 + r0;
        Wt[(size_t)(n0 + r) * DIM_ + k0 + c] = (_Float16)t[c][r];
    }
}

// ---------------------------------------------------------------------------
// Occupancy-2 pipelined MFMA GEMM: BM x 128 tile, BK=32, 8 waves (4M x 2N),
// per-wave 64x64 (acc=64 regs -> 2 blocks/CU), 3 LDS buffers, counted
// vmcnt(LPT), ONE barrier per K-tile. 2-way-max bank swizzle
// slot ^= (R ^ (R>>2)) & 3 (write side pre-swizzles global source).
// C = A[M,K] * Bt[N,K]^T ; N split into 2048-col output segments.
// ---------------------------------------------------------------------------
template <int BM, typename OT>
__global__ __launch_bounds__(512, 4) void gemmp(const _Float16* __restrict__ A,
                                                const _Float16* __restrict__ Bt,
                                                OT* __restrict__ C0, OT* __restrict__ C1,
                                                OT* __restrict__ C2, OT* __restrict__ C3,
                                                int K, int nx, int cpx)
{
    constexpr int BN   = 128;
    constexpr int LPT  = (BM + BN) / 128;   // stage loads per thread per K-tile
    constexpr int WR   = BM / 4;            // rows per wave
    constexpr int MF   = WR / 16;           // A frags per wave
    constexpr int ASZ  = BM * 32;           // A halfs per buffer
    constexpr int DSZ  = (BM + BN) * 32;    // halfs per buffer
    __shared__ _Float16 lds[3 * DSZ];

    const int tid = threadIdx.x;
    const int lane = tid & 63, w = tid >> 6;
    const int wr = w >> 1, wc = w & 1;
    const int l15 = lane & 15, l16 = lane >> 4;

    const int bid = blockIdx.x;
    const int swz = (bid & 7) * cpx + (bid >> 3);   // XCD swizzle (nwg%8==0)
    const int bm = (swz / nx) * BM, bn = (swz % nx) * BN;

    // stage addressing: F = 16B-unit id; R = F>>2 (row), s = F&3 (slot).
    // LDS dest linear; global source slot = s ^ (R ^ (R>>2)) & 3 (involution).
    const _Float16* src[LPT];
    int ldst[LPT];
#pragma unroll
    for (int ld = 0; ld < LPT; ++ld) {
        int F = ld * 512 + tid;
        int R = F >> 2;
        int sc = ((F & 3) ^ (R ^ (R >> 2))) & 3;
        src[ld] = (R < BM) ? A + (size_t)(bm + R) * K + sc * 8
                           : Bt + (size_t)(bn + R - BM) * K + sc * 8;
        ldst[ld] = F * 8;
    }

    // fragment read offsets (halfs), same swizzle
    int aoff[MF], boff[4];
#pragma unroll
    for (int m = 0; m < MF; ++m) {
        int R = wr * WR + m * 16 + l15;
        aoff[m] = R * 32 + (((l16 ^ R ^ (R >> 2)) & 3) * 8);
    }
#pragma unroll
    for (int n = 0; n < 4; ++n) {
        int R = wc * 64 + n * 16 + l15;
        boff[n] = ASZ + R * 32 + (((l16 ^ R ^ (R >> 2)) & 3) * 8);
    }

    f32x4 acc[MF][4] = {};
    const int nt = K >> 5;

#define STAGE(kt, buf) do { _Pragma("unroll")                                  \
    for (int ld_ = 0; ld_ < LPT; ++ld_)                                        \
        gload16(src[ld_] + (size_t)(kt) * 32, lds + (buf) * DSZ + ldst[ld_]);  \
    } while (0)
#define VM_STEADY() do { if constexpr (LPT == 3) VMW(3); else VMW(2); } while (0)

    STAGE(0, 0);
    STAGE(1, 1);
    VM_STEADY();                           // own tile-0 loads landed
    __builtin_amdgcn_s_barrier();          // all waves' tile 0 landed
    __builtin_amdgcn_sched_barrier(0);

    int cb = 0, nb = 2;
    for (int t = 0; t < nt; ++t) {
        const _Float16* L = lds + cb * DSZ;
        half8 af[MF], bf[4];
#pragma unroll
        for (int m = 0; m < MF; ++m) af[m] = *(const half8*)(L + aoff[m]);
#pragma unroll
        for (int n = 0; n < 4; ++n) bf[n] = *(const half8*)(L + boff[n]);

        const bool pf = (t + 2 < nt);
        if (pf) STAGE(t + 2, nb);

        asm volatile("s_waitcnt lgkmcnt(0)" ::: "memory");
        __builtin_amdgcn_sched_barrier(0);
        __builtin_amdgcn_s_setprio(1);
#pragma unroll
        for (int m = 0; m < MF; ++m)
#pragma unroll
            for (int n = 0; n < 4; ++n)
                acc[m][n] = __builtin_amdgcn_mfma_f32_16x16x32_f16(af[m], bf[n], acc[m][n], 0, 0, 0);
        __builtin_amdgcn_s_setprio(0);
        __builtin_amdgcn_sched_barrier(0);

        if (pf) VM_STEADY();               // tile t+1 landed (per-wave FIFO)
        else    VMW(0);
        __builtin_amdgcn_s_barrier();      // tile t+1 landed block-wide
        __builtin_amdgcn_sched_barrier(0);

        cb = (cb == 2) ? 0 : cb + 1;
        nb = (nb == 2) ? 0 : nb + 1;
    }
#undef STAGE
#undef VM_STEADY

    const int sel = bn >> 11;
    OT* __restrict__ C = sel == 0 ? C0 : sel == 1 ? C1 : sel == 2 ? C2 : C3;
    const int crb = bm + wr * WR;
    const int ccb = (bn & 2047) + wc * 64;
#pragma unroll
    for (int m = 0; m < MF; ++m)
#pragma unroll
        for (int n = 0; n < 4; ++n)
#pragma unroll
            for (int r = 0; r < 4; ++r)
                C[(size_t)(crb + m * 16 + l16 * 4 + r) * 2048 + ccb + n * 16 + l15] =
                    (OT)acc[m][n][r];
}

// ---------------------------------------------------------------------------
// conv_all: y=0 -> q conv+silu; y=1 -> v conv; y=2 -> k conv+silu+L2norm.
// ---------------------------------------------------------------------------
__global__ __launch_bounds__(256) void conv_all(const _Float16* __restrict__ pq,
                                                const _Float16* __restrict__ pk,
                                                const _Float16* __restrict__ pv,
                                                const float* __restrict__ qw,
                                                const float* __restrict__ qb,
                                                const float* __restrict__ kw,
                                                const float* __restrict__ kb,
                                                const float* __restrict__ vw,
                                                const float* __restrict__ vb,
                                                _Float16* __restrict__ qh,
                                                _Float16* __restrict__ kh,
                                                _Float16* __restrict__ vh)
{
    const int y = blockIdx.y;
    if (y == 2) {   // k conv + silu + L2 normalize, wave per (b,t,h) row
        if (blockIdx.x >= (B_ * T_ * H_) / 4) return;
        int lane = threadIdx.x & 63, wv = threadIdx.x >> 6;
        size_t r = (size_t)blockIdx.x * 4 + wv;
        int h = (int)(r & 15);
        size_t gr = r >> 4;
        int t = (int)(gr & (T_ - 1));
        int c0 = h * 128 + lane * 2;

        float a0 = kb[c0], a1 = kb[c0 + 1];
#pragma unroll
        for (int j = 0; j < 4; ++j) {
            int ts = t - 3 + j;
            if (ts >= 0) {
                const _Float16* p = pk + (gr - 3 + j) * DIM_ + c0;
                a0 += (float)p[0] * kw[c0 * 4 + j];
                a1 += (float)p[1] * kw[(c0 + 1) * 4 + j];
            }
        }
        a0 = a0 * sigmoidf_(a0);
        a1 = a1 * sigmoidf_(a1);
        float ss = a0 * a0 + a1 * a1;
#pragma unroll
        for (int off = 1; off < 64; off <<= 1) ss += __shfl_xor(ss, off);
        float sc = 1.0f / fmaxf(sqrtf(ss), 1e-12f);
        kh[gr * DIM_ + c0]     = (_Float16)(a0 * sc);
        kh[gr * DIM_ + c0 + 1] = (_Float16)(a1 * sc);
        return;
    }
    const int act = (y == 0);
    const _Float16* xin = act ? pq : pv;
    const float* w = act ? qw : vw;
    const float* bias = act ? qb : vb;
    _Float16* yo = act ? qh : vh;

    size_t idx = (size_t)blockIdx.x * 256 + threadIdx.x;
    int cc = (int)(idx & (DIM_ - 1));
    int t = (int)((idx >> 11) & (T_ - 1));
    int b = (int)(idx >> 22);
    float acc = bias[cc];
    const _Float16* xc = xin + (size_t)b * T_ * DIM_ + cc;
#pragma unroll
    for (int j = 0; j < 4; ++j) {
        int ts = t - 3 + j;
        if (ts >= 0) acc += (float)xc[(size_t)ts * DIM_] * w[cc * 4 + j];
    }
    if (act) acc = acc * sigmoidf_(acc);
    yo[idx] = (_Float16)acc;
}

// ---------------------------------------------------------------------------
// R1: per (bh, chunk) U_c = sum_s bet*decay^(63-s) * v_s k_s^T  (128x128 f16)
// ---------------------------------------------------------------------------
__global__ __launch_bounds__(256) void r1_kernel(const _Float16* __restrict__ kh,
                                                 const _Float16* __restrict__ vh,
                                                 const float* __restrict__ A_log,
                                                 const float* __restrict__ beta,
                                                 _Float16* __restrict__ U)
{
    const int c = blockIdx.x & 31, bh = blockIdx.x >> 5;
    const int h = bh & 15, b = bh >> 4;
    const float decay = sigmoidf_(A_log[h]);
    const float bet = sigmoidf_(beta[h]);
    const float ld = logf(decay);

    __shared__ _Float16 kt[128][72];
    __shared__ _Float16 vt[128][72];

    const int tid = threadIdx.x;
    const size_t base = ((size_t)(b * T_ + c * 64) * H_ + h) * 128;
    for (int rep = 0; rep < 32; ++rep) {
        int idx = rep * 256 + tid;
        int s = idx >> 7, i = idx & 127;
        float kv = (float)kh[base + (size_t)s * DIM_ + i];
        float vv = (float)vh[base + (size_t)s * DIM_ + i];
        kt[i][s] = (_Float16)kv;
        vt[i][s] = (_Float16)(bet * __expf(ld * (float)(63 - s)) * vv);
    }
    __syncthreads();

    const int lane = tid & 63, w = tid >> 6;
    const int l15 = lane & 15, l16 = lane >> 4;
    f32x4 acc[2][8] = {};
#pragma unroll
    for (int ks = 0; ks < 2; ++ks) {
        half8 a0 = *(const half8*)&vt[w * 32 + l15][ks * 32 + l16 * 8];
        half8 a1 = *(const half8*)&vt[w * 32 + 16 + l15][ks * 32 + l16 * 8];
#pragma unroll
        for (int fj = 0; fj < 8; ++fj) {
            half8 bf = *(const half8*)&kt[fj * 16 + l15][ks * 32 + l16 * 8];
            acc[0][fj] = __builtin_amdgcn_mfma_f32_16x16x32_f16(a0, bf, acc[0][fj], 0, 0, 0);
            acc[1][fj] = __builtin_amdgcn_mfma_f32_16x16x32_f16(a1, bf, acc[1][fj], 0, 0, 0);
        }
    }
    _Float16* Ub = U + (((size_t)blockIdx.x) << 14);
#pragma unroll
    for (int fi = 0; fi < 2; ++fi)
#pragma unroll
        for (int fj = 0; fj < 8; ++fj)
#pragma unroll
            for (int r = 0; r < 4; ++r) {
                int i = w * 32 + fi * 16 + l16 * 4 + r;
                int j = fj * 16 + l15;
                Ub[i * 128 + j] = (_Float16)acc[fi][fj][r];
            }
}

// ---------------------------------------------------------------------------
// R2: chunk-boundary state scan, parallel over (bh, 2048-elem slices).
// ---------------------------------------------------------------------------
__global__ __launch_bounds__(256) void r2_kernel(const _Float16* __restrict__ U,
                                                 _Float16* __restrict__ S,
                                                 const float* __restrict__ A_log)
{
    const int blk = blockIdx.x;
    const int bh = blk >> 3, part = blk & 7, h = bh & 15;
    const float decay = sigmoidf_(A_log[h]);
    const float d64 = __expf(64.0f * logf(decay));
    const size_t base = ((size_t)bh << 19) + (size_t)part * 2048 + (size_t)threadIdx.x * 8;
    const half8* Up = (const half8*)(U + base);
    half8* Sp = (half8*)(S + base);

    float st[8] = {0, 0, 0, 0, 0, 0, 0, 0};
    half8 n0 = Up[0];
    half8 n1 = Up[2048];
    for (int c = 0; c < 32; ++c) {
        half8 cur = n0;
        n0 = n1;
        if (c + 2 < 32) n1 = Up[(size_t)(c + 2) * 2048];
        half8 so;
#pragma unroll
        for (int i = 0; i < 8; ++i) {
            so[i] = (_Float16)st[i];
            st[i] = d64 * st[i] + (float)cur[i];
        }
        Sp[(size_t)c * 2048] = so;
    }
}

// ---------------------------------------------------------------------------
// R3: per (bh, chunk): out = mask(QK^T)V + rowscale(Q S^T); gate fused.
// ---------------------------------------------------------------------------
__global__ __launch_bounds__(256) void r3_kernel(const _Float16* __restrict__ qh,
                                                 const _Float16* __restrict__ kh,
                                                 const _Float16* __restrict__ vh,
                                                 const _Float16* __restrict__ S,
                                                 const _Float16* __restrict__ pg,
                                                 const float* __restrict__ A_log,
                                                 const float* __restrict__ beta,
                                                 _Float16* __restrict__ gated)
{
    const int c = blockIdx.x & 31, bh = blockIdx.x >> 5;
    const int h = bh & 15, b = bh >> 4;
    const float decay = sigmoidf_(A_log[h]);
    const float bet = sigmoidf_(beta[h]);
    const float ld = logf(decay);

    __shared__ _Float16 vt[128][72];
    __shared__ _Float16 ps[64][72];

    const int tid = threadIdx.x;
    const size_t base = ((size_t)(b * T_ + c * 64) * H_ + h) * 128;
    for (int rep = 0; rep < 32; ++rep) {
        int idx = rep * 256 + tid;
        int s = idx >> 7, n = idx & 127;
        vt[n][s] = vh[base + (size_t)s * DIM_ + n];
    }
    __syncthreads();

    const int lane = tid & 63, w = tid >> 6;
    const int l15 = lane & 15, l16 = lane >> 4;

    const _Float16* qrow = qh + base + (size_t)(w * 16 + l15) * DIM_;
    half8 af[4];
#pragma unroll
    for (int kd = 0; kd < 4; ++kd) af[kd] = *(const half8*)(qrow + kd * 32 + l16 * 8);

    f32x4 pacc[4] = {};
    const _Float16* kb = kh + base;
#pragma unroll
    for (int sf = 0; sf < 4; ++sf)
#pragma unroll
        for (int kd = 0; kd < 4; ++kd) {
            half8 bf = *(const half8*)(kb + (size_t)(sf * 16 + l15) * DIM_ + kd * 32 + l16 * 8);
            pacc[sf] = __builtin_amdgcn_mfma_f32_16x16x32_f16(af[kd], bf, pacc[sf], 0, 0, 0);
        }
#pragma unroll
    for (int sf = 0; sf < 4; ++sf)
#pragma unroll
        for (int r = 0; r < 4; ++r) {
            int tl = w * 16 + l16 * 4 + r;
            int s = sf * 16 + l15;
            float f = (s <= tl) ? bet * __expf(ld * (float)(tl - s)) : 0.0f;
            ps[tl][s] = (_Float16)(pacc[sf][r] * f);
        }
    __syncthreads();

    half8 pf[2];
#pragma unroll
    for (int ks = 0; ks < 2; ++ks)
        pf[ks] = *(const half8*)&ps[w * 16 + l15][ks * 32 + l16 * 8];

    f32x4 acc1[8] = {};
    f32x4 acc2[8] = {};
    const _Float16* Sb = S + (((size_t)blockIdx.x) << 14);
#pragma unroll
    for (int nf = 0; nf < 8; ++nf) {
#pragma unroll
        for (int kd = 0; kd < 4; ++kd) {
            half8 bf = *(const half8*)(Sb + (size_t)(nf * 16 + l15) * 128 + kd * 32 + l16 * 8);
            acc1[nf] = __builtin_amdgcn_mfma_f32_16x16x32_f16(af[kd], bf, acc1[nf], 0, 0, 0);
        }
#pragma unroll
        for (int ks = 0; ks < 2; ++ks) {
            half8 bf = *(const half8*)&vt[nf * 16 + l15][ks * 32 + l16 * 8];
            acc2[nf] = __builtin_amdgcn_mfma_f32_16x16x32_f16(pf[ks], bf, acc2[nf], 0, 0, 0);
        }
    }
#pragma unroll
    for (int nf = 0; nf < 8; ++nf)
#pragma unroll
        for (int r = 0; r < 4; ++r) {
            int tl = w * 16 + l16 * 4 + r;
            int n = nf * 16 + l15;
            size_t row = (size_t)(b * T_ + c * 64 + tl);
            float o = acc2[nf][r] + __expf(ld * (float)(tl + 1)) * acc1[nf][r];
            float g = (float)pg[row * DIM_ + h * 128 + n];
            gated[row * DIM_ + h * 128 + n] = (_Float16)(o * sigmoidf_(g));
        }
}

// ---------------------------------------------------------------------------
extern "C" void kernel_launch(void* const* d_in, const int* in_sizes, int n_in,
                              void* d_out, int out_size, void* d_ws, size_t ws_size,
                              hipStream_t stream)
{
    const float* x     = (const float*)d_in[0];
    const float* Wq    = (const float*)d_in[1];
    const float* Wk    = (const float*)d_in[2];
    const float* Wv    = (const float*)d_in[3];
    const float* Wo    = (const float*)d_in[4];
    const float* Wg    = (const float*)d_in[5];
    const float* qw    = (const float*)d_in[6];
    const float* qb    = (const float*)d_in[7];
    const float* kw    = (const float*)d_in[8];
    const float* kb    = (const float*)d_in[9];
    const float* vw    = (const float*)d_in[10];
    const float* vb    = (const float*)d_in[11];
    const float* beta  = (const float*)d_in[12];
    const float* A_log = (const float*)d_in[13];
    float* out = (float*)d_out;

    char* wsb = (char*)d_ws;
    const size_t WT  = (size_t)DIM_ * DIM_ * 2;
    const size_t SZ  = (size_t)B_ * T_ * DIM_;
    const size_t SZH = SZ * 2;

    _Float16* wtq = (_Float16*)(wsb + 0 * WT);    // wtq..wtg contiguous = Bt[8192][2048]
    _Float16* wto = (_Float16*)(wsb + 4 * WT);
    char* pbase = wsb + 5 * WT;
    _Float16* pq = (_Float16*)(pbase + 0 * SZH);
    _Float16* pk = (_Float16*)(pbase + 1 * SZH);
    _Float16* pv = (_Float16*)(pbase + 2 * SZH);
    _Float16* xh = (_Float16*)(pbase + 3 * SZH);
    _Float16* pg = (_Float16*)(pbase + 4 * SZH);
    _Float16* qh = (_Float16*)(pbase + 5 * SZH);
    _Float16* kh = (_Float16*)(pbase + 6 * SZH);
    _Float16* vh = (_Float16*)(pbase + 7 * SZH);
    _Float16* U     = pq;  // 32 MB, spans pq+pk (dead after convs)
    _Float16* Sst   = pv;  // 32 MB, spans pv+xh (dead after conv_v / GEMMs)
    _Float16* gated = pq;  // 16 MB, U dead after r2

    // cvt + 5 weight transposes in one launch
    prep<<<dim3(32, 32, 6), 256, 0, stream>>>(Wq, Wk, Wv, Wg, Wo, wtq, x, xh);

    // fused projections: M=4096, N=8192 (q|k|v|g): 16x64 = 1024 tiles 256x128
    gemmp<256, _Float16><<<1024, 512, 0, stream>>>(xh, wtq, pq, pk, pv, pg,
                                                   DIM_, 64, 128);

    // q conv / v conv / k conv+norm in one launch
    conv_all<<<dim3((int)(SZ / 256), 3), 256, 0, stream>>>(pq, pk, pv,
                                                           qw, qb, kw, kb, vw, vb,
                                                           qh, kh, vh);

    r1_kernel<<<B_ * H_ * 32, 256, 0, stream>>>(kh, vh, A_log, beta, U);
    r2_kernel<<<256, 256, 0, stream>>>(U, Sst, A_log);
    r3_kernel<<<B_ * H_ * 32, 256, 0, stream>>>(qh, kh, vh, Sst, pg, A_log, beta, gated);

    // out = gated @ Wo : M=4096, N=2048 -> 32x16 = 512 tiles of 128x128
    gemmp<128, float><<<512, 512, 0, stream>>>(gated, wto, out, out, out, out,
                                               DIM_, 16, 64);
}

// Round 8
// 444.217 us; speedup vs baseline: 1.0094x; 1.0094x over previous
//
#include <hip/hip_runtime.h>
#include <math.h>

#define B_   2
#define T_   2048
#define DIM_ 2048
#define H_   16

typedef __attribute__((ext_vector_type(8))) _Float16 half8;
typedef __attribute__((ext_vector_type(4))) _Float16 half4;
typedef __attribute__((ext_vector_type(4))) float f32x4;

__device__ __forceinline__ float sigmoidf_(float x) { return 1.0f / (1.0f + __expf(-x)); }

__device__ __forceinline__ void gload16(const _Float16* g, _Float16* l) {
    __builtin_amdgcn_global_load_lds((const __attribute__((address_space(1))) void*)g,
                                     (__attribute__((address_space(3))) void*)l, 16, 0, 0);
}

#define VMW(n) asm volatile("s_waitcnt vmcnt(" #n ")" ::: "memory")

// ---------------------------------------------------------------------------
// prep: z<5 -> weight transpose W[K][N] f32 -> Wt[N][K] f16; z==5 -> x cvt.
// ---------------------------------------------------------------------------
__global__ __launch_bounds__(256) void prep(const float* __restrict__ W0,
                                            const float* __restrict__ W1,
                                            const float* __restrict__ W2,
                                            const float* __restrict__ W3,
                                            const float* __restrict__ W4,
                                            _Float16* __restrict__ wbase,
                                            const float* __restrict__ x,
                                            _Float16* __restrict__ xh)
{
    const int z = blockIdx.z;
    if (z == 5) {   // cvt: 1024 blocks x 32 elems/thread
        size_t blk = ((size_t)blockIdx.y * 32 + blockIdx.x) * 8192;
#pragma unroll
        for (int j = 0; j < 4; ++j) {
            size_t i = blk + (size_t)j * 2048 + (size_t)threadIdx.x * 8;
            float4 a = *(const float4*)(x + i);
            float4 b = *(const float4*)(x + i + 4);
            half8 h;
            h[0] = (_Float16)a.x; h[1] = (_Float16)a.y; h[2] = (_Float16)a.z; h[3] = (_Float16)a.w;
            h[4] = (_Float16)b.x; h[5] = (_Float16)b.y; h[6] = (_Float16)b.z; h[7] = (_Float16)b.w;
            *(half8*)(xh + i) = h;
        }
        return;
    }
    __shared__ float t[64][65];
    const float* W = z == 0 ? W0 : z == 1 ? W1 : z == 2 ? W2 : z == 3 ? W3 : W4;
    _Float16* Wt = wbase + (size_t)z * DIM_ * DIM_;
    const int c = threadIdx.x & 63;
    const int r0 = threadIdx.x >> 6;
    const int n0 = blockIdx.x * 64, k0 = blockIdx.y * 64;
#pragma unroll
    for (int i = 0; i < 16; ++i) {
        int r = i * 4 + r0;
        t[r][c] = W[(size_t)(k0 + r) * DIM_ + n0 + c];
    }
    __syncthreads();
#pragma unroll
    for (int i = 0; i < 16; ++i) {
        int r = i * 4 + r0;
        Wt[(size_t)(n0 + r) * DIM_ + k0 + c] = (_Float16)t[c][r];
    }
}

// ---------------------------------------------------------------------------
// Occupancy-2 pipelined MFMA GEMM: BM x 128 tile, BK=32, 8 waves (4M x 2N),
// per-wave 64x64 (acc=64 regs -> 2 blocks/CU), 3 LDS buffers, counted
// vmcnt(LPT), ONE barrier per K-tile. Swizzle: round-4-verified pattern
// slot_bit1 ^= row_bit3 (zero measured bank conflicts), applied on the
// pre-swizzled global source (write side) and fragment reads (read side).
// C = A[M,K] * Bt[N,K]^T ; N split into 2048-col output segments.
// ---------------------------------------------------------------------------
template <int BM, typename OT>
__global__ __launch_bounds__(512, 4) void gemmp(const _Float16* __restrict__ A,
                                                const _Float16* __restrict__ Bt,
                                                OT* __restrict__ C0, OT* __restrict__ C1,
                                                OT* __restrict__ C2, OT* __restrict__ C3,
                                                int K, int nx, int cpx)
{
    constexpr int BN   = 128;
    constexpr int LPT  = (BM + BN) / 128;   // stage loads per thread per K-tile
    constexpr int WR   = BM / 4;            // rows per wave
    constexpr int MF   = WR / 16;           // A frags per wave
    constexpr int ASZ  = BM * 32;           // A halfs per buffer
    constexpr int DSZ  = (BM + BN) * 32;    // halfs per buffer
    __shared__ _Float16 lds[3 * DSZ];

    const int tid = threadIdx.x;
    const int lane = tid & 63, w = tid >> 6;
    const int wr = w >> 1, wc = w & 1;
    const int l15 = lane & 15, l16 = lane >> 4;

    const int bid = blockIdx.x;
    const int swz = (bid & 7) * cpx + (bid >> 3);   // XCD swizzle (nwg%8==0)
    const int bm = (swz / nx) * BM, bn = (swz % nx) * BN;

    // stage addressing: F = 16B-unit id; R = F>>2 (row), s = F&3 (slot).
    // LDS dest linear; global source slot = s ^ (((R>>3)&1)<<1)  [round-4
    // verified zero-conflict swizzle].
    const _Float16* src[LPT];
    int ldst[LPT];
#pragma unroll
    for (int ld = 0; ld < LPT; ++ld) {
        int F = ld * 512 + tid;
        int R = F >> 2;
        int sc = (F & 3) ^ (((R >> 3) & 1) << 1);
        src[ld] = (R < BM) ? A + (size_t)(bm + R) * K + sc * 8
                           : Bt + (size_t)(bn + R - BM) * K + sc * 8;
        ldst[ld] = F * 8;
    }

    // fragment read offsets (halfs), same swizzle
    int aoff[MF], boff[4];
#pragma unroll
    for (int m = 0; m < MF; ++m) {
        int R = wr * WR + m * 16 + l15;
        aoff[m] = R * 32 + ((l16 ^ (((R >> 3) & 1) << 1)) * 8);
    }
#pragma unroll
    for (int n = 0; n < 4; ++n) {
        int R = wc * 64 + n * 16 + l15;
        boff[n] = ASZ + R * 32 + ((l16 ^ (((R >> 3) & 1) << 1)) * 8);
    }

    f32x4 acc[MF][4] = {};
    const int nt = K >> 5;

#define STAGE(kt, buf) do { _Pragma("unroll")                                  \
    for (int ld_ = 0; ld_ < LPT; ++ld_)                                        \
        gload16(src[ld_] + (size_t)(kt) * 32, lds + (buf) * DSZ + ldst[ld_]);  \
    } while (0)
#define VM_STEADY() do { if constexpr (LPT == 3) VMW(3); else VMW(2); } while (0)

    STAGE(0, 0);
    STAGE(1, 1);
    VM_STEADY();                           // own tile-0 loads landed
    __builtin_amdgcn_s_barrier();          // all waves' tile 0 landed
    __builtin_amdgcn_sched_barrier(0);

    int cb = 0, nb = 2;
    for (int t = 0; t < nt; ++t) {
        const _Float16* L = lds + cb * DSZ;
        half8 af[MF], bf[4];
#pragma unroll
        for (int m = 0; m < MF; ++m) af[m] = *(const half8*)(L + aoff[m]);
#pragma unroll
        for (int n = 0; n < 4; ++n) bf[n] = *(const half8*)(L + boff[n]);

        const bool pf = (t + 2 < nt);
        if (pf) STAGE(t + 2, nb);

        asm volatile("s_waitcnt lgkmcnt(0)" ::: "memory");
        __builtin_amdgcn_sched_barrier(0);
        __builtin_amdgcn_s_setprio(1);
#pragma unroll
        for (int m = 0; m < MF; ++m)
#pragma unroll
            for (int n = 0; n < 4; ++n)
                acc[m][n] = __builtin_amdgcn_mfma_f32_16x16x32_f16(af[m], bf[n], acc[m][n], 0, 0, 0);
        __builtin_amdgcn_s_setprio(0);
        __builtin_amdgcn_sched_barrier(0);

        if (pf) VM_STEADY();               // tile t+1 landed (per-wave FIFO)
        else    VMW(0);
        __builtin_amdgcn_s_barrier();      // tile t+1 landed block-wide
        __builtin_amdgcn_sched_barrier(0);

        cb = (cb == 2) ? 0 : cb + 1;
        nb = (nb == 2) ? 0 : nb + 1;
    }
#undef STAGE
#undef VM_STEADY

    const int sel = bn >> 11;
    OT* __restrict__ C = sel == 0 ? C0 : sel == 1 ? C1 : sel == 2 ? C2 : C3;
    const int crb = bm + wr * WR;
    const int ccb = (bn & 2047) + wc * 64;
#pragma unroll
    for (int m = 0; m < MF; ++m)
#pragma unroll
        for (int n = 0; n < 4; ++n)
#pragma unroll
            for (int r = 0; r < 4; ++r)
                C[(size_t)(crb + m * 16 + l16 * 4 + r) * 2048 + ccb + n * 16 + l15] =
                    (OT)acc[m][n][r];
}

// ---------------------------------------------------------------------------
// conv_all: y=0 -> q conv+silu; y=1 -> v conv; y=2 -> k conv+silu+L2norm.
// ---------------------------------------------------------------------------
__global__ __launch_bounds__(256) void conv_all(const _Float16* __restrict__ pq,
                                                const _Float16* __restrict__ pk,
                                                const _Float16* __restrict__ pv,
                                                const float* __restrict__ qw,
                                                const float* __restrict__ qb,
                                                const float* __restrict__ kw,
                                                const float* __restrict__ kb,
                                                const float* __restrict__ vw,
                                                const float* __restrict__ vb,
                                                _Float16* __restrict__ qh,
                                                _Float16* __restrict__ kh,
                                                _Float16* __restrict__ vh)
{
    const int y = blockIdx.y;
    if (y == 2) {   // k conv + silu + L2 normalize, wave per (b,t,h) row
        if (blockIdx.x >= (B_ * T_ * H_) / 4) return;
        int lane = threadIdx.x & 63, wv = threadIdx.x >> 6;
        size_t r = (size_t)blockIdx.x * 4 + wv;
        int h = (int)(r & 15);
        size_t gr = r >> 4;
        int t = (int)(gr & (T_ - 1));
        int c0 = h * 128 + lane * 2;

        float a0 = kb[c0], a1 = kb[c0 + 1];
#pragma unroll
        for (int j = 0; j < 4; ++j) {
            int ts = t - 3 + j;
            if (ts >= 0) {
                const _Float16* p = pk + (gr - 3 + j) * DIM_ + c0;
                a0 += (float)p[0] * kw[c0 * 4 + j];
                a1 += (float)p[1] * kw[(c0 + 1) * 4 + j];
            }
        }
        a0 = a0 * sigmoidf_(a0);
        a1 = a1 * sigmoidf_(a1);
        float ss = a0 * a0 + a1 * a1;
#pragma unroll
        for (int off = 1; off < 64; off <<= 1) ss += __shfl_xor(ss, off);
        float sc = 1.0f / fmaxf(sqrtf(ss), 1e-12f);
        kh[gr * DIM_ + c0]     = (_Float16)(a0 * sc);
        kh[gr * DIM_ + c0 + 1] = (_Float16)(a1 * sc);
        return;
    }
    const int act = (y == 0);
    const _Float16* xin = act ? pq : pv;
    const float* w = act ? qw : vw;
    const float* bias = act ? qb : vb;
    _Float16* yo = act ? qh : vh;

    size_t idx = (size_t)blockIdx.x * 256 + threadIdx.x;
    int cc = (int)(idx & (DIM_ - 1));
    int t = (int)((idx >> 11) & (T_ - 1));
    int b = (int)(idx >> 22);
    float acc = bias[cc];
    const _Float16* xc = xin + (size_t)b * T_ * DIM_ + cc;
#pragma unroll
    for (int j = 0; j < 4; ++j) {
        int ts = t - 3 + j;
        if (ts >= 0) acc += (float)xc[(size_t)ts * DIM_] * w[cc * 4 + j];
    }
    if (act) acc = acc * sigmoidf_(acc);
    yo[idx] = (_Float16)acc;
}

// ---------------------------------------------------------------------------
// R1: per (bh, chunk) U_c = sum_s bet*decay^(63-s) * v_s k_s^T  (128x128 f16)
// ---------------------------------------------------------------------------
__global__ __launch_bounds__(256) void r1_kernel(const _Float16* __restrict__ kh,
                                                 const _Float16* __restrict__ vh,
                                                 const float* __restrict__ A_log,
                                                 const float* __restrict__ beta,
                                                 _Float16* __restrict__ U)
{
    const int c = blockIdx.x & 31, bh = blockIdx.x >> 5;
    const int h = bh & 15, b = bh >> 4;
    const float decay = sigmoidf_(A_log[h]);
    const float bet = sigmoidf_(beta[h]);
    const float ld = logf(decay);

    __shared__ _Float16 kt[128][72];
    __shared__ _Float16 vt[128][72];

    const int tid = threadIdx.x;
    const size_t base = ((size_t)(b * T_ + c * 64) * H_ + h) * 128;
    for (int rep = 0; rep < 32; ++rep) {
        int idx = rep * 256 + tid;
        int s = idx >> 7, i = idx & 127;
        float kv = (float)kh[base + (size_t)s * DIM_ + i];
        float vv = (float)vh[base + (size_t)s * DIM_ + i];
        kt[i][s] = (_Float16)kv;
        vt[i][s] = (_Float16)(bet * __expf(ld * (float)(63 - s)) * vv);
    }
    __syncthreads();

    const int lane = tid & 63, w = tid >> 6;
    const int l15 = lane & 15, l16 = lane >> 4;
    f32x4 acc[2][8] = {};
#pragma unroll
    for (int ks = 0; ks < 2; ++ks) {
        half8 a0 = *(const half8*)&vt[w * 32 + l15][ks * 32 + l16 * 8];
        half8 a1 = *(const half8*)&vt[w * 32 + 16 + l15][ks * 32 + l16 * 8];
#pragma unroll
        for (int fj = 0; fj < 8; ++fj) {
            half8 bf = *(const half8*)&kt[fj * 16 + l15][ks * 32 + l16 * 8];
            acc[0][fj] = __builtin_amdgcn_mfma_f32_16x16x32_f16(a0, bf, acc[0][fj], 0, 0, 0);
            acc[1][fj] = __builtin_amdgcn_mfma_f32_16x16x32_f16(a1, bf, acc[1][fj], 0, 0, 0);
        }
    }
    _Float16* Ub = U + (((size_t)blockIdx.x) << 14);
#pragma unroll
    for (int fi = 0; fi < 2; ++fi)
#pragma unroll
        for (int fj = 0; fj < 8; ++fj)
#pragma unroll
            for (int r = 0; r < 4; ++r) {
                int i = w * 32 + fi * 16 + l16 * 4 + r;
                int j = fj * 16 + l15;
                Ub[i * 128 + j] = (_Float16)acc[fi][fj][r];
            }
}

// ---------------------------------------------------------------------------
// R2: chunk-boundary state scan, parallel over (bh, 2048-elem slices).
// ---------------------------------------------------------------------------
__global__ __launch_bounds__(256) void r2_kernel(const _Float16* __restrict__ U,
                                                 _Float16* __restrict__ S,
                                                 const float* __restrict__ A_log)
{
    const int blk = blockIdx.x;
    const int bh = blk >> 3, part = blk & 7, h = bh & 15;
    const float decay = sigmoidf_(A_log[h]);
    const float d64 = __expf(64.0f * logf(decay));
    const size_t base = ((size_t)bh << 19) + (size_t)part * 2048 + (size_t)threadIdx.x * 8;
    const half8* Up = (const half8*)(U + base);
    half8* Sp = (half8*)(S + base);

    float st[8] = {0, 0, 0, 0, 0, 0, 0, 0};
    half8 n0 = Up[0];
    half8 n1 = Up[2048];
    for (int c = 0; c < 32; ++c) {
        half8 cur = n0;
        n0 = n1;
        if (c + 2 < 32) n1 = Up[(size_t)(c + 2) * 2048];
        half8 so;
#pragma unroll
        for (int i = 0; i < 8; ++i) {
            so[i] = (_Float16)st[i];
            st[i] = d64 * st[i] + (float)cur[i];
        }
        Sp[(size_t)c * 2048] = so;
    }
}

// ---------------------------------------------------------------------------
// R3: per (bh, chunk): out = mask(QK^T)V + rowscale(Q S^T); gate fused.
// ---------------------------------------------------------------------------
__global__ __launch_bounds__(256) void r3_kernel(const _Float16* __restrict__ qh,
                                                 const _Float16* __restrict__ kh,
                                                 const _Float16* __restrict__ vh,
                                                 const _Float16* __restrict__ S,
                                                 const _Float16* __restrict__ pg,
                                                 const float* __restrict__ A_log,
                                                 const float* __restrict__ beta,
                                                 _Float16* __restrict__ gated)
{
    const int c = blockIdx.x & 31, bh = blockIdx.x >> 5;
    const int h = bh & 15, b = bh >> 4;
    const float decay = sigmoidf_(A_log[h]);
    const float bet = sigmoidf_(beta[h]);
    const float ld = logf(decay);

    __shared__ _Float16 vt[128][72];
    __shared__ _Float16 ps[64][72];

    const int tid = threadIdx.x;
    const size_t base = ((size_t)(b * T_ + c * 64) * H_ + h) * 128;
    for (int rep = 0; rep < 32; ++rep) {
        int idx = rep * 256 + tid;
        int s = idx >> 7, n = idx & 127;
        vt[n][s] = vh[base + (size_t)s * DIM_ + n];
    }
    __syncthreads();

    const int lane = tid & 63, w = tid >> 6;
    const int l15 = lane & 15, l16 = lane >> 4;

    const _Float16* qrow = qh + base + (size_t)(w * 16 + l15) * DIM_;
    half8 af[4];
#pragma unroll
    for (int kd = 0; kd < 4; ++kd) af[kd] = *(const half8*)(qrow + kd * 32 + l16 * 8);

    f32x4 pacc[4] = {};
    const _Float16* kb = kh + base;
#pragma unroll
    for (int sf = 0; sf < 4; ++sf)
#pragma unroll
        for (int kd = 0; kd < 4; ++kd) {
            half8 bf = *(const half8*)(kb + (size_t)(sf * 16 + l15) * DIM_ + kd * 32 + l16 * 8);
            pacc[sf] = __builtin_amdgcn_mfma_f32_16x16x32_f16(af[kd], bf, pacc[sf], 0, 0, 0);
        }
#pragma unroll
    for (int sf = 0; sf < 4; ++sf)
#pragma unroll
        for (int r = 0; r < 4; ++r) {
            int tl = w * 16 + l16 * 4 + r;
            int s = sf * 16 + l15;
            float f = (s <= tl) ? bet * __expf(ld * (float)(tl - s)) : 0.0f;
            ps[tl][s] = (_Float16)(pacc[sf][r] * f);
        }
    __syncthreads();

    half8 pf[2];
#pragma unroll
    for (int ks = 0; ks < 2; ++ks)
        pf[ks] = *(const half8*)&ps[w * 16 + l15][ks * 32 + l16 * 8];

    f32x4 acc1[8] = {};
    f32x4 acc2[8] = {};
    const _Float16* Sb = S + (((size_t)blockIdx.x) << 14);
#pragma unroll
    for (int nf = 0; nf < 8; ++nf) {
#pragma unroll
        for (int kd = 0; kd < 4; ++kd) {
            half8 bf = *(const half8*)(Sb + (size_t)(nf * 16 + l15) * 128 + kd * 32 + l16 * 8);
            acc1[nf] = __builtin_amdgcn_mfma_f32_16x16x32_f16(af[kd], bf, acc1[nf], 0, 0, 0);
        }
#pragma unroll
        for (int ks = 0; ks < 2; ++ks) {
            half8 bf = *(const half8*)&vt[nf * 16 + l15][ks * 32 + l16 * 8];
            acc2[nf] = __builtin_amdgcn_mfma_f32_16x16x32_f16(pf[ks], bf, acc2[nf], 0, 0, 0);
        }
    }
#pragma unroll
    for (int nf = 0; nf < 8; ++nf)
#pragma unroll
        for (int r = 0; r < 4; ++r) {
            int tl = w * 16 + l16 * 4 + r;
            int n = nf * 16 + l15;
            size_t row = (size_t)(b * T_ + c * 64 + tl);
            float o = acc2[nf][r] + __expf(ld * (float)(tl + 1)) * acc1[nf][r];
            float g = (float)pg[row * DIM_ + h * 128 + n];
            gated[row * DIM_ + h * 128 + n] = (_Float16)(o * sigmoidf_(g));
        }
}

// ---------------------------------------------------------------------------
extern "C" void kernel_launch(void* const* d_in, const int* in_sizes, int n_in,
                              void* d_out, int out_size, void* d_ws, size_t ws_size,
                              hipStream_t stream)
{
    const float* x     = (const float*)d_in[0];
    const float* Wq    = (const float*)d_in[1];
    const float* Wk    = (const float*)d_in[2];
    const float* Wv    = (const float*)d_in[3];
    const float* Wo    = (const float*)d_in[4];
    const float* Wg    = (const float*)d_in[5];
    const float* qw    = (const float*)d_in[6];
    const float* qb    = (const float*)d_in[7];
    const float* kw    = (const float*)d_in[8];
    const float* kb    = (const float*)d_in[9];
    const float* vw    = (const float*)d_in[10];
    const float* vb    = (const float*)d_in[11];
    const float* beta  = (const float*)d_in[12];
    const float* A_log = (const float*)d_in[13];
    float* out = (float*)d_out;

    char* wsb = (char*)d_ws;
    const size_t WT  = (size_t)DIM_ * DIM_ * 2;
    const size_t SZ  = (size_t)B_ * T_ * DIM_;
    const size_t SZH = SZ * 2;

    _Float16* wtq = (_Float16*)(wsb + 0 * WT);    // wtq..wtg contiguous = Bt[8192][2048]
    _Float16* wto = (_Float16*)(wsb + 4 * WT);
    char* pbase = wsb + 5 * WT;
    _Float16* pq = (_Float16*)(pbase + 0 * SZH);
    _Float16* pk = (_Float16*)(pbase + 1 * SZH);
    _Float16* pv = (_Float16*)(pbase + 2 * SZH);
    _Float16* xh = (_Float16*)(pbase + 3 * SZH);
    _Float16* pg = (_Float16*)(pbase + 4 * SZH);
    _Float16* qh = (_Float16*)(pbase + 5 * SZH);
    _Float16* kh = (_Float16*)(pbase + 6 * SZH);
    _Float16* vh = (_Float16*)(pbase + 7 * SZH);
    _Float16* U     = pq;  // 32 MB, spans pq+pk (dead after convs)
    _Float16* Sst   = pv;  // 32 MB, spans pv+xh (dead after conv_v / GEMMs)
    _Float16* gated = pq;  // 16 MB, U dead after r2

    // cvt + 5 weight transposes in one launch
    prep<<<dim3(32, 32, 6), 256, 0, stream>>>(Wq, Wk, Wv, Wg, Wo, wtq, x, xh);

    // fused projections: M=4096, N=8192 (q|k|v|g): 16x64 = 1024 tiles 256x128
    gemmp<256, _Float16><<<1024, 512, 0, stream>>>(xh, wtq, pq, pk, pv, pg,
                                                   DIM_, 64, 128);

    // q conv / v conv / k conv+norm in one launch
    conv_all<<<dim3((int)(SZ / 256), 3), 256, 0, stream>>>(pq, pk, pv,
                                                           qw, qb, kw, kb, vw, vb,
                                                           qh, kh, vh);

    r1_kernel<<<B_ * H_ * 32, 256, 0, stream>>>(kh, vh, A_log, beta, U);
    r2_kernel<<<256, 256, 0, stream>>>(U, Sst, A_log);
    r3_kernel<<<B_ * H_ * 32, 256, 0, stream>>>(qh, kh, vh, Sst, pg, A_log, beta, gated);

    // out = gated @ Wo : M=4096, N=2048 -> 32x16 = 512 tiles of 128x128
    gemmp<128, float><<<512, 512, 0, stream>>>(gated, wto, out, out, out, out,
                                               DIM_, 16, 64);
}

// Round 9
// 424.252 us; speedup vs baseline: 1.0569x; 1.0471x over previous
//
#include <hip/hip_runtime.h>
#include <math.h>

#define B_   2
#define T_   2048
#define DIM_ 2048
#define H_   16

typedef __attribute__((ext_vector_type(8))) _Float16 half8;
typedef __attribute__((ext_vector_type(4))) float f32x4;

__device__ __forceinline__ float sigmoidf_(float x) { return 1.0f / (1.0f + __expf(-x)); }

__device__ __forceinline__ void gload16(const _Float16* g, _Float16* l) {
    __builtin_amdgcn_global_load_lds((const __attribute__((address_space(1))) void*)g,
                                     (__attribute__((address_space(3))) void*)l, 16, 0, 0);
}

#define VMW(n) asm volatile("s_waitcnt vmcnt(" #n ")" ::: "memory")

// Swizzled transpose-LDS addressing for [row][72] f16 tiles holding [row][s]
// (s<64). Physical s-chunk = (s>>3) ^ ((row>>3)&7); keeps half8 reads aligned,
// spreads stride-8-row writes across banks (2-way max = free).
__device__ __forceinline__ int tsw(int row, int s) {
    return row * 72 + ((((s >> 3) ^ ((row >> 3) & 7)) << 3) | (s & 7));
}
__device__ __forceinline__ int tswb(int row, int sb) {  // half8 chunk base
    return row * 72 + (((sb ^ ((row >> 3) & 7)) << 3));
}

// ---------------------------------------------------------------------------
// prep: z<5 -> weight transpose W[K][N] f32 -> Wt[N][K] f16; z==5 -> x cvt.
// ---------------------------------------------------------------------------
__global__ __launch_bounds__(256) void prep(const float* __restrict__ W0,
                                            const float* __restrict__ W1,
                                            const float* __restrict__ W2,
                                            const float* __restrict__ W3,
                                            const float* __restrict__ W4,
                                            _Float16* __restrict__ wbase,
                                            const float* __restrict__ x,
                                            _Float16* __restrict__ xh)
{
    const int z = blockIdx.z;
    if (z == 5) {   // cvt: 1024 blocks x 32 elems/thread
        size_t blk = ((size_t)blockIdx.y * 32 + blockIdx.x) * 8192;
#pragma unroll
        for (int j = 0; j < 4; ++j) {
            size_t i = blk + (size_t)j * 2048 + (size_t)threadIdx.x * 8;
            float4 a = *(const float4*)(x + i);
            float4 b = *(const float4*)(x + i + 4);
            half8 h;
            h[0] = (_Float16)a.x; h[1] = (_Float16)a.y; h[2] = (_Float16)a.z; h[3] = (_Float16)a.w;
            h[4] = (_Float16)b.x; h[5] = (_Float16)b.y; h[6] = (_Float16)b.z; h[7] = (_Float16)b.w;
            *(half8*)(xh + i) = h;
        }
        return;
    }
    __shared__ float t[64][65];
    const float* W = z == 0 ? W0 : z == 1 ? W1 : z == 2 ? W2 : z == 3 ? W3 : W4;
    _Float16* Wt = wbase + (size_t)z * DIM_ * DIM_;
    const int c = threadIdx.x & 63;
    const int r0 = threadIdx.x >> 6;
    const int n0 = blockIdx.x * 64, k0 = blockIdx.y * 64;
#pragma unroll
    for (int i = 0; i < 16; ++i) {
        int r = i * 4 + r0;
        t[r][c] = W[(size_t)(k0 + r) * DIM_ + n0 + c];
    }
    __syncthreads();
#pragma unroll
    for (int i = 0; i < 16; ++i) {
        int r = i * 4 + r0;
        Wt[(size_t)(n0 + r) * DIM_ + k0 + c] = (_Float16)t[c][r];
    }
}

// ---------------------------------------------------------------------------
// Occupancy-2 pipelined MFMA GEMM: BM x 128 tile, BK=32, 8 waves (4M x 2N),
// 3 LDS buffers, counted vmcnt, 1 barrier per K-tile, round-4-verified
// swizzle (slot_bit1 ^= row_bit3). Epilogue: LDS bounce -> coalesced vector
// C stores. C = A[M,K] * Bt[N,K]^T ; N split into 2048-col output segments.
// ---------------------------------------------------------------------------
template <int BM, typename OT>
__global__ __launch_bounds__(512, 4) void gemmp(const _Float16* __restrict__ A,
                                                const _Float16* __restrict__ Bt,
                                                OT* __restrict__ C0, OT* __restrict__ C1,
                                                OT* __restrict__ C2, OT* __restrict__ C3,
                                                int K, int nx, int cpx)
{
    constexpr int BN   = 128;
    constexpr int LPT  = (BM + BN) / 128;
    constexpr int WR   = BM / 4;
    constexpr int MF   = WR / 16;
    constexpr int ASZ  = BM * 32;
    constexpr int DSZ  = (BM + BN) * 32;
    constexpr int BW   = (sizeof(OT) == 2) ? 136 : 132;   // bounce row width
    constexpr size_t STAGEB = (size_t)3 * DSZ * 2;
    constexpr size_t BOUNB  = (size_t)BM * BW * sizeof(OT);
    constexpr size_t LB = STAGEB > BOUNB ? STAGEB : BOUNB;
    __shared__ alignas(16) char ldsraw[LB];
    _Float16* lds = reinterpret_cast<_Float16*>(ldsraw);

    const int tid = threadIdx.x;
    const int lane = tid & 63, w = tid >> 6;
    const int wr = w >> 1, wc = w & 1;
    const int l15 = lane & 15, l16 = lane >> 4;

    const int bid = blockIdx.x;
    const int swz = (bid & 7) * cpx + (bid >> 3);   // XCD swizzle (nwg%8==0)
    const int bm = (swz / nx) * BM, bn = (swz % nx) * BN;

    const _Float16* src[LPT];
    int ldst[LPT];
#pragma unroll
    for (int ld = 0; ld < LPT; ++ld) {
        int F = ld * 512 + tid;
        int R = F >> 2;
        int sc = (F & 3) ^ (((R >> 3) & 1) << 1);
        src[ld] = (R < BM) ? A + (size_t)(bm + R) * K + sc * 8
                           : Bt + (size_t)(bn + R - BM) * K + sc * 8;
        ldst[ld] = F * 8;
    }

    int aoff[MF], boff[4];
#pragma unroll
    for (int m = 0; m < MF; ++m) {
        int R = wr * WR + m * 16 + l15;
        aoff[m] = R * 32 + ((l16 ^ (((R >> 3) & 1) << 1)) * 8);
    }
#pragma unroll
    for (int n = 0; n < 4; ++n) {
        int R = wc * 64 + n * 16 + l15;
        boff[n] = ASZ + R * 32 + ((l16 ^ (((R >> 3) & 1) << 1)) * 8);
    }

    f32x4 acc[MF][4] = {};
    const int nt = K >> 5;

#define STAGE(kt, buf) do { _Pragma("unroll")                                  \
    for (int ld_ = 0; ld_ < LPT; ++ld_)                                        \
        gload16(src[ld_] + (size_t)(kt) * 32, lds + (buf) * DSZ + ldst[ld_]);  \
    } while (0)
#define VM_STEADY() do { if constexpr (LPT == 3) VMW(3); else VMW(2); } while (0)

    STAGE(0, 0);
    STAGE(1, 1);
    VM_STEADY();
    __builtin_amdgcn_s_barrier();
    __builtin_amdgcn_sched_barrier(0);

    int cb = 0, nb = 2;
    for (int t = 0; t < nt; ++t) {
        const _Float16* L = lds + cb * DSZ;
        half8 af[MF], bf[4];
#pragma unroll
        for (int m = 0; m < MF; ++m) af[m] = *(const half8*)(L + aoff[m]);
#pragma unroll
        for (int n = 0; n < 4; ++n) bf[n] = *(const half8*)(L + boff[n]);

        const bool pf = (t + 2 < nt);
        if (pf) STAGE(t + 2, nb);

        asm volatile("s_waitcnt lgkmcnt(0)" ::: "memory");
        __builtin_amdgcn_sched_barrier(0);
        __builtin_amdgcn_s_setprio(1);
#pragma unroll
        for (int m = 0; m < MF; ++m)
#pragma unroll
            for (int n = 0; n < 4; ++n)
                acc[m][n] = __builtin_amdgcn_mfma_f32_16x16x32_f16(af[m], bf[n], acc[m][n], 0, 0, 0);
        __builtin_amdgcn_s_setprio(0);
        __builtin_amdgcn_sched_barrier(0);

        if (pf) VM_STEADY();
        else    VMW(0);
        __builtin_amdgcn_s_barrier();
        __builtin_amdgcn_sched_barrier(0);

        cb = (cb == 2) ? 0 : cb + 1;
        nb = (nb == 2) ? 0 : nb + 1;
    }
#undef STAGE
#undef VM_STEADY

    // epilogue: bounce through LDS, then coalesced 16B stores
    OT* bb = reinterpret_cast<OT*>(ldsraw);
#pragma unroll
    for (int m = 0; m < MF; ++m)
#pragma unroll
        for (int n = 0; n < 4; ++n)
#pragma unroll
            for (int r = 0; r < 4; ++r)
                bb[(wr * WR + m * 16 + l16 * 4 + r) * BW + wc * 64 + n * 16 + l15] =
                    (OT)acc[m][n][r];
    __syncthreads();

    const int sel = bn >> 11;
    OT* __restrict__ C = sel == 0 ? C0 : sel == 1 ? C1 : sel == 2 ? C2 : C3;
    const int ccol0 = bn & 2047;
    constexpr int VE = 16 / sizeof(OT);     // elems per 16B
    constexpr int CPR = 128 / VE;           // chunks per row
#pragma unroll
    for (int rep = 0; rep < (BM * CPR) / 512; ++rep) {
        int u = rep * 512 + tid;
        int i = u / CPR, q = u % CPR;
        if constexpr (sizeof(OT) == 2)
            *reinterpret_cast<half8*>(C + (size_t)(bm + i) * 2048 + ccol0 + q * VE) =
                *reinterpret_cast<const half8*>(bb + i * BW + q * VE);
        else
            *reinterpret_cast<float4*>(C + (size_t)(bm + i) * 2048 + ccol0 + q * VE) =
                *reinterpret_cast<const float4*>(bb + i * BW + q * VE);
    }
}

// ---------------------------------------------------------------------------
// conv_all: y=0 -> q conv+silu (8ch/thread); y=1 -> v conv; y=2 -> k+norm.
// ---------------------------------------------------------------------------
__global__ __launch_bounds__(256) void conv_all(const _Float16* __restrict__ pq,
                                                const _Float16* __restrict__ pk,
                                                const _Float16* __restrict__ pv,
                                                const float* __restrict__ qw,
                                                const float* __restrict__ qb,
                                                const float* __restrict__ kw,
                                                const float* __restrict__ kb,
                                                const float* __restrict__ vw,
                                                const float* __restrict__ vb,
                                                _Float16* __restrict__ qh,
                                                _Float16* __restrict__ kh,
                                                _Float16* __restrict__ vh)
{
    const int y = blockIdx.y;
    if (y == 2) {   // k conv + silu + L2 normalize, wave per (b,t,h) row
        int lane = threadIdx.x & 63, wv = threadIdx.x >> 6;
        size_t r = (size_t)blockIdx.x * 4 + wv;
        int h = (int)(r & 15);
        size_t gr = r >> 4;
        int t = (int)(gr & (T_ - 1));
        int c0 = h * 128 + lane * 2;

        float a0 = kb[c0], a1 = kb[c0 + 1];
#pragma unroll
        for (int j = 0; j < 4; ++j) {
            int ts = t - 3 + j;
            if (ts >= 0) {
                const _Float16* p = pk + (gr - 3 + j) * DIM_ + c0;
                a0 += (float)p[0] * kw[c0 * 4 + j];
                a1 += (float)p[1] * kw[(c0 + 1) * 4 + j];
            }
        }
        a0 = a0 * sigmoidf_(a0);
        a1 = a1 * sigmoidf_(a1);
        float ss = a0 * a0 + a1 * a1;
#pragma unroll
        for (int off = 1; off < 64; off <<= 1) ss += __shfl_xor(ss, off);
        float sc = 1.0f / fmaxf(sqrtf(ss), 1e-12f);
        kh[gr * DIM_ + c0]     = (_Float16)(a0 * sc);
        kh[gr * DIM_ + c0 + 1] = (_Float16)(a1 * sc);
        return;
    }
    if (blockIdx.x >= 4096) return;
    const int act = (y == 0);
    const _Float16* xin = act ? pq : pv;
    const float* w = act ? qw : vw;
    const float* bias = act ? qb : vb;
    _Float16* yo = act ? qh : vh;

    int idx = blockIdx.x * 256 + threadIdx.x;       // 0..1M-1, 8 ch each
    int c8 = (idx & 255) * 8;
    int t = (idx >> 8) & (T_ - 1);
    int b = idx >> 19;
    const size_t rowbase = ((size_t)b * T_ + t) * DIM_ + c8;

    float4 w4[8];
    float accv[8];
#pragma unroll
    for (int u = 0; u < 8; ++u) {
        w4[u] = *(const float4*)(w + (c8 + u) * 4);
        accv[u] = bias[c8 + u];
    }
    const _Float16* xc = xin + rowbase;
#pragma unroll
    for (int j = 0; j < 4; ++j) {
        int ts = t - 3 + j;
        if (ts >= 0) {
            half8 xv = *(const half8*)(xc + (ptrdiff_t)(j - 3) * DIM_);
            const float* wj = (const float*)&w4[0];
#pragma unroll
            for (int u = 0; u < 8; ++u)
                accv[u] += (float)xv[u] * ((const float*)&w4[u])[j];
            (void)wj;
        }
    }
    half8 o;
#pragma unroll
    for (int u = 0; u < 8; ++u) {
        float v = accv[u];
        if (act) v = v * sigmoidf_(v);
        o[u] = (_Float16)v;
    }
    *(half8*)(yo + rowbase) = o;
}

// ---------------------------------------------------------------------------
// R1: per (bh, chunk) U_c = sum_s bet*decay^(63-s) * v_s k_s^T  (128x128 f16)
// Vector loads, exp table, swizzled transpose-LDS, bounce-vectorized store.
// ---------------------------------------------------------------------------
__global__ __launch_bounds__(256) void r1_kernel(const _Float16* __restrict__ kh,
                                                 const _Float16* __restrict__ vh,
                                                 const float* __restrict__ A_log,
                                                 const float* __restrict__ beta,
                                                 _Float16* __restrict__ U)
{
    const int c = blockIdx.x & 31, bh = blockIdx.x >> 5;
    const int h = bh & 15, b = bh >> 4;
    const float decay = sigmoidf_(A_log[h]);
    const float bet = sigmoidf_(beta[h]);
    const float ld = logf(decay);

    __shared__ _Float16 sm[2 * 128 * 72];   // kt | vt ; reused as bounce buf
    __shared__ float pw[64];
    _Float16* kt = sm;                      // [d][s] swizzled (tsw)
    _Float16* vt = sm + 128 * 72;           // [v][s] swizzled

    const int tid = threadIdx.x;
    if (tid < 64) pw[tid] = bet * __expf(ld * (float)(63 - tid));
    __syncthreads();

    const size_t base = ((size_t)(b * T_ + c * 64) * H_ + h) * 128;
#pragma unroll
    for (int rep = 0; rep < 4; ++rep) {
        int idx = rep * 256 + tid;          // 1024 units: 64 s x 16 dq
        int s = idx >> 4, dq = idx & 15;
        half8 kv = *(const half8*)(kh + base + (size_t)s * DIM_ + dq * 8);
        half8 vv = *(const half8*)(vh + base + (size_t)s * DIM_ + dq * 8);
        float sc = pw[s];
#pragma unroll
        for (int j = 0; j < 8; ++j) {
            kt[tsw(dq * 8 + j, s)] = kv[j];
            vt[tsw(dq * 8 + j, s)] = (_Float16)(sc * (float)vv[j]);
        }
    }
    __syncthreads();

    const int lane = tid & 63, w = tid >> 6;
    const int l15 = lane & 15, l16 = lane >> 4;
    f32x4 acc[2][8] = {};
#pragma unroll
    for (int ks = 0; ks < 2; ++ks) {
        half8 a0 = *(const half8*)(vt + tswb(w * 32 + l15,      ks * 4 + l16));
        half8 a1 = *(const half8*)(vt + tswb(w * 32 + 16 + l15, ks * 4 + l16));
#pragma unroll
        for (int fj = 0; fj < 8; ++fj) {
            half8 bf = *(const half8*)(kt + tswb(fj * 16 + l15, ks * 4 + l16));
            acc[0][fj] = __builtin_amdgcn_mfma_f32_16x16x32_f16(a0, bf, acc[0][fj], 0, 0, 0);
            acc[1][fj] = __builtin_amdgcn_mfma_f32_16x16x32_f16(a1, bf, acc[1][fj], 0, 0, 0);
        }
    }
    __syncthreads();   // kt/vt reads done; reuse sm as bounce [128][136]

    _Float16* buf = sm;
#pragma unroll
    for (int fi = 0; fi < 2; ++fi)
#pragma unroll
        for (int fj = 0; fj < 8; ++fj)
#pragma unroll
            for (int r = 0; r < 4; ++r)
                buf[(w * 32 + fi * 16 + l16 * 4 + r) * 136 + fj * 16 + l15] =
                    (_Float16)acc[fi][fj][r];
    __syncthreads();

    _Float16* Ub = U + (((size_t)blockIdx.x) << 14);
#pragma unroll
    for (int rep = 0; rep < 8; ++rep) {
        int u = rep * 256 + tid;            // 2048 units
        int i = u >> 4, jq = u & 15;
        *(half8*)(Ub + i * 128 + jq * 8) = *(const half8*)(buf + i * 136 + jq * 8);
    }
}

// ---------------------------------------------------------------------------
// R2: chunk-boundary state scan, parallel over (bh, 2048-elem slices).
// ---------------------------------------------------------------------------
__global__ __launch_bounds__(256) void r2_kernel(const _Float16* __restrict__ U,
                                                 _Float16* __restrict__ S,
                                                 const float* __restrict__ A_log)
{
    const int blk = blockIdx.x;
    const int bh = blk >> 3, part = blk & 7, h = bh & 15;
    const float decay = sigmoidf_(A_log[h]);
    const float d64 = __expf(64.0f * logf(decay));
    const size_t base = ((size_t)bh << 19) + (size_t)part * 2048 + (size_t)threadIdx.x * 8;
    const half8* Up = (const half8*)(U + base);
    half8* Sp = (half8*)(S + base);

    float st[8] = {0, 0, 0, 0, 0, 0, 0, 0};
    half8 n0 = Up[0];
    half8 n1 = Up[2048];
    for (int c = 0; c < 32; ++c) {
        half8 cur = n0;
        n0 = n1;
        if (c + 2 < 32) n1 = Up[(size_t)(c + 2) * 2048];
        half8 so;
#pragma unroll
        for (int i = 0; i < 8; ++i) {
            so[i] = (_Float16)st[i];
            st[i] = d64 * st[i] + (float)cur[i];
        }
        Sp[(size_t)c * 2048] = so;
    }
}

// ---------------------------------------------------------------------------
// R3: per (bh, chunk): out = mask(QK^T)V + rowscale(Q S^T); gate fused.
// Vector loads, exp table, swizzled vt, bounce-vectorized gated store.
// ---------------------------------------------------------------------------
__global__ __launch_bounds__(256) void r3_kernel(const _Float16* __restrict__ qh,
                                                 const _Float16* __restrict__ kh,
                                                 const _Float16* __restrict__ vh,
                                                 const _Float16* __restrict__ S,
                                                 const _Float16* __restrict__ pg,
                                                 const float* __restrict__ A_log,
                                                 const float* __restrict__ beta,
                                                 _Float16* __restrict__ gated)
{
    const int c = blockIdx.x & 31, bh = blockIdx.x >> 5;
    const int h = bh & 15, b = bh >> 4;
    const float decay = sigmoidf_(A_log[h]);
    const float bet = sigmoidf_(beta[h]);
    const float ld = logf(decay);

    __shared__ _Float16 vt[128 * 72];       // [n][s] swizzled (tsw)
    __shared__ _Float16 ps[64][72];
    __shared__ _Float16 buf[64 * 136];      // out bounce
    __shared__ float e1[65];

    const int tid = threadIdx.x;
    if (tid < 65) e1[tid] = __expf(ld * (float)tid);

    const size_t base = ((size_t)(b * T_ + c * 64) * H_ + h) * 128;
#pragma unroll
    for (int rep = 0; rep < 4; ++rep) {
        int idx = rep * 256 + tid;          // 1024 units: 64 s x 16 nq
        int s = idx >> 4, nq = idx & 15;
        half8 vv = *(const half8*)(vh + base + (size_t)s * DIM_ + nq * 8);
#pragma unroll
        for (int j = 0; j < 8; ++j)
            vt[tsw(nq * 8 + j, s)] = vv[j];
    }
    __syncthreads();

    const int lane = tid & 63, w = tid >> 6;
    const int l15 = lane & 15, l16 = lane >> 4;

    const _Float16* qrow = qh + base + (size_t)(w * 16 + l15) * DIM_;
    half8 af[4];
#pragma unroll
    for (int kd = 0; kd < 4; ++kd) af[kd] = *(const half8*)(qrow + kd * 32 + l16 * 8);

    f32x4 pacc[4] = {};
    const _Float16* kb = kh + base;
#pragma unroll
    for (int sf = 0; sf < 4; ++sf)
#pragma unroll
        for (int kd = 0; kd < 4; ++kd) {
            half8 bf = *(const half8*)(kb + (size_t)(sf * 16 + l15) * DIM_ + kd * 32 + l16 * 8);
            pacc[sf] = __builtin_amdgcn_mfma_f32_16x16x32_f16(af[kd], bf, pacc[sf], 0, 0, 0);
        }
#pragma unroll
    for (int sf = 0; sf < 4; ++sf)
#pragma unroll
        for (int r = 0; r < 4; ++r) {
            int tl = w * 16 + l16 * 4 + r;
            int s = sf * 16 + l15;
            float f = (s <= tl) ? bet * e1[tl - s] : 0.0f;
            ps[tl][s] = (_Float16)(pacc[sf][r] * f);
        }
    __syncthreads();

    half8 pf[2];
#pragma unroll
    for (int ks = 0; ks < 2; ++ks)
        pf[ks] = *(const half8*)&ps[w * 16 + l15][ks * 32 + l16 * 8];

    f32x4 acc1[8] = {};
    f32x4 acc2[8] = {};
    const _Float16* Sb = S + (((size_t)blockIdx.x) << 14);
#pragma unroll
    for (int nf = 0; nf < 8; ++nf) {
#pragma unroll
        for (int kd = 0; kd < 4; ++kd) {
            half8 bf = *(const half8*)(Sb + (size_t)(nf * 16 + l15) * 128 + kd * 32 + l16 * 8);
            acc1[nf] = __builtin_amdgcn_mfma_f32_16x16x32_f16(af[kd], bf, acc1[nf], 0, 0, 0);
        }
#pragma unroll
        for (int ks = 0; ks < 2; ++ks) {
            half8 bf = *(const half8*)(vt + tswb(nf * 16 + l15, ks * 4 + l16));
            acc2[nf] = __builtin_amdgcn_mfma_f32_16x16x32_f16(pf[ks], bf, acc2[nf], 0, 0, 0);
        }
    }
    // bounce the 64x128 out tile, then gate with vectorized pg loads
#pragma unroll
    for (int nf = 0; nf < 8; ++nf)
#pragma unroll
        for (int r = 0; r < 4; ++r) {
            int tl = w * 16 + l16 * 4 + r;
            float o = acc2[nf][r] + e1[tl + 1] * acc1[nf][r];
            buf[tl * 136 + nf * 16 + l15] = (_Float16)o;
        }
    __syncthreads();

#pragma unroll
    for (int rep = 0; rep < 4; ++rep) {
        int u = rep * 256 + tid;            // 1024 units
        int tl = u >> 4, jq = u & 15;
        size_t row = (size_t)(b * T_ + c * 64 + tl);
        half8 o8 = *(const half8*)(buf + tl * 136 + jq * 8);
        half8 g8 = *(const half8*)(pg + row * DIM_ + h * 128 + jq * 8);
        half8 r8;
#pragma unroll
        for (int j = 0; j < 8; ++j)
            r8[j] = (_Float16)((float)o8[j] * sigmoidf_((float)g8[j]));
        *(half8*)(gated + row * DIM_ + h * 128 + jq * 8) = r8;
    }
}

// ---------------------------------------------------------------------------
extern "C" void kernel_launch(void* const* d_in, const int* in_sizes, int n_in,
                              void* d_out, int out_size, void* d_ws, size_t ws_size,
                              hipStream_t stream)
{
    const float* x     = (const float*)d_in[0];
    const float* Wq    = (const float*)d_in[1];
    const float* Wk    = (const float*)d_in[2];
    const float* Wv    = (const float*)d_in[3];
    const float* Wo    = (const float*)d_in[4];
    const float* Wg    = (const float*)d_in[5];
    const float* qw    = (const float*)d_in[6];
    const float* qb    = (const float*)d_in[7];
    const float* kw    = (const float*)d_in[8];
    const float* kb    = (const float*)d_in[9];
    const float* vw    = (const float*)d_in[10];
    const float* vb    = (const float*)d_in[11];
    const float* beta  = (const float*)d_in[12];
    const float* A_log = (const float*)d_in[13];
    float* out = (float*)d_out;

    char* wsb = (char*)d_ws;
    const size_t WT  = (size_t)DIM_ * DIM_ * 2;
    const size_t SZ  = (size_t)B_ * T_ * DIM_;
    const size_t SZH = SZ * 2;

    _Float16* wtq = (_Float16*)(wsb + 0 * WT);    // wtq..wtg contiguous = Bt[8192][2048]
    _Float16* wto = (_Float16*)(wsb + 4 * WT);
    char* pbase = wsb + 5 * WT;
    _Float16* pq = (_Float16*)(pbase + 0 * SZH);
    _Float16* pk = (_Float16*)(pbase + 1 * SZH);
    _Float16* pv = (_Float16*)(pbase + 2 * SZH);
    _Float16* xh = (_Float16*)(pbase + 3 * SZH);
    _Float16* pg = (_Float16*)(pbase + 4 * SZH);
    _Float16* qh = (_Float16*)(pbase + 5 * SZH);
    _Float16* kh = (_Float16*)(pbase + 6 * SZH);
    _Float16* vh = (_Float16*)(pbase + 7 * SZH);
    _Float16* U     = pq;  // 32 MB, spans pq+pk (dead after convs)
    _Float16* Sst   = pv;  // 32 MB, spans pv+xh (dead after conv_v / GEMMs)
    _Float16* gated = pq;  // 16 MB, U dead after r2

    // cvt + 5 weight transposes in one launch
    prep<<<dim3(32, 32, 6), 256, 0, stream>>>(Wq, Wk, Wv, Wg, Wo, wtq, x, xh);

    // fused projections: M=4096, N=8192 (q|k|v|g): 16x64 = 1024 tiles 256x128
    gemmp<256, _Float16><<<1024, 512, 0, stream>>>(xh, wtq, pq, pk, pv, pg,
                                                   DIM_, 64, 128);

    // q conv / v conv / k conv+norm in one launch
    conv_all<<<dim3(16384, 3), 256, 0, stream>>>(pq, pk, pv,
                                                 qw, qb, kw, kb, vw, vb,
                                                 qh, kh, vh);

    r1_kernel<<<B_ * H_ * 32, 256, 0, stream>>>(kh, vh, A_log, beta, U);
    r2_kernel<<<256, 256, 0, stream>>>(U, Sst, A_log);
    r3_kernel<<<B_ * H_ * 32, 256, 0, stream>>>(qh, kh, vh, Sst, pg, A_log, beta, gated);

    // out = gated @ Wo : M=4096, N=2048 -> 32x16 = 512 tiles of 128x128
    gemmp<128, float><<<512, 512, 0, stream>>>(gated, wto, out, out, out, out,
                                               DIM_, 16, 64);
}

// Round 10
// 389.777 us; speedup vs baseline: 1.1504x; 1.0884x over previous
//
#include <hip/hip_runtime.h>
#include <math.h>

#define B_   2
#define T_   2048
#define DIM_ 2048
#define H_   16

typedef __attribute__((ext_vector_type(8))) _Float16 half8;
typedef __attribute__((ext_vector_type(4))) float f32x4;

__device__ __forceinline__ float sigmoidf_(float x) { return 1.0f / (1.0f + __expf(-x)); }

__device__ __forceinline__ void gload16(const _Float16* g, _Float16* l) {
    __builtin_amdgcn_global_load_lds((const __attribute__((address_space(1))) void*)g,
                                     (__attribute__((address_space(3))) void*)l, 16, 0, 0);
}

#define VMW(n) asm volatile("s_waitcnt vmcnt(" #n ")" ::: "memory")

// Swizzled transpose-LDS addressing for [row][72] f16 tiles holding [row][s].
__device__ __forceinline__ int tsw(int row, int s) {
    return row * 72 + ((((s >> 3) ^ ((row >> 3) & 7)) << 3) | (s & 7));
}
__device__ __forceinline__ int tswb(int row, int sb) {
    return row * 72 + (((sb ^ ((row >> 3) & 7)) << 3));
}

// ---------------------------------------------------------------------------
// prep: z<5 -> weight transpose W[K][N] f32 -> Wt[N][K] f16; z==5 -> x cvt.
// ---------------------------------------------------------------------------
__global__ __launch_bounds__(256) void prep(const float* __restrict__ W0,
                                            const float* __restrict__ W1,
                                            const float* __restrict__ W2,
                                            const float* __restrict__ W3,
                                            const float* __restrict__ W4,
                                            _Float16* __restrict__ wbase,
                                            const float* __restrict__ x,
                                            _Float16* __restrict__ xh)
{
    const int z = blockIdx.z;
    if (z == 5) {
        size_t blk = ((size_t)blockIdx.y * 32 + blockIdx.x) * 8192;
#pragma unroll
        for (int j = 0; j < 4; ++j) {
            size_t i = blk + (size_t)j * 2048 + (size_t)threadIdx.x * 8;
            float4 a = *(const float4*)(x + i);
            float4 b = *(const float4*)(x + i + 4);
            half8 h;
            h[0] = (_Float16)a.x; h[1] = (_Float16)a.y; h[2] = (_Float16)a.z; h[3] = (_Float16)a.w;
            h[4] = (_Float16)b.x; h[5] = (_Float16)b.y; h[6] = (_Float16)b.z; h[7] = (_Float16)b.w;
            *(half8*)(xh + i) = h;
        }
        return;
    }
    __shared__ float t[64][65];
    const float* W = z == 0 ? W0 : z == 1 ? W1 : z == 2 ? W2 : z == 3 ? W3 : W4;
    _Float16* Wt = wbase + (size_t)z * DIM_ * DIM_;
    const int c = threadIdx.x & 63;
    const int r0 = threadIdx.x >> 6;
    const int n0 = blockIdx.x * 64, k0 = blockIdx.y * 64;
#pragma unroll
    for (int i = 0; i < 16; ++i) {
        int r = i * 4 + r0;
        t[r][c] = W[(size_t)(k0 + r) * DIM_ + n0 + c];
    }
    __syncthreads();
#pragma unroll
    for (int i = 0; i < 16; ++i) {
        int r = i * 4 + r0;
        Wt[(size_t)(n0 + r) * DIM_ + k0 + c] = (_Float16)t[c][r];
    }
}

// ---------------------------------------------------------------------------
// 8-phase pipelined MFMA GEMM (round-6 variant, measured-best 141 us on proj):
// 256x256 tile, BK=64, 2 K-tiles/iter, 8 waves (2M x 4N), counted vmcnt(4),
// 3-bit XOR LDS swizzle, f16 output. Epilogue: two-pass LDS bounce ->
// coalesced half8 stores. C = A[M,K] * Bt[N,K]^T ; N split in 2048-col segs.
// ---------------------------------------------------------------------------
template <int BM>
__global__ __launch_bounds__(512, 1) void gemm8ph(const _Float16* __restrict__ A,
                                                  const _Float16* __restrict__ Bt,
                                                  _Float16* __restrict__ C0, _Float16* __restrict__ C1,
                                                  _Float16* __restrict__ C2, _Float16* __restrict__ C3,
                                                  int K, int nx, int cpx)
{
    constexpr int MF  = BM / 32;
    constexpr int AQ  = MF / 4;
    constexpr int ASZ = BM * 64;
    constexpr int DSZ = (BM + 256) * 64;
    __shared__ _Float16 lds[2 * DSZ];

    const int tid = threadIdx.x;
    const int lane = tid & 63, w = tid >> 6;
    const int wr = w >> 2, wc = w & 3;
    const int l15 = lane & 15, l16 = lane >> 4;

    const int bid = blockIdx.x;
    const int swz = (bid & 7) * cpx + (bid >> 3);
    const int bm = (swz / nx) * BM, bn = (swz % nx) * 256;

    const int r0 = tid >> 3;
    const int c0 = ((tid & 7) ^ (r0 & 7)) * 8;
    const _Float16* Ab = A + (size_t)(bm + r0) * K + c0;
    const _Float16* Bb = Bt + (size_t)(bn + r0) * K + c0;

#define STAGE_A(d, kt) do { _Pragma("unroll")                                    \
    for (int u = 0; u < BM / 64; ++u)                                            \
        gload16(Ab + (size_t)(u * 64) * K + (size_t)(kt) * 64,                   \
                lds + (d) * DSZ + u * 4096 + tid * 8); } while (0)
#define STAGE_B(d, h, kt) do {                                                   \
    gload16(Bb + (size_t)((h) * 128) * K + (size_t)(kt) * 64,                    \
            lds + (d) * DSZ + ASZ + (h) * 8192 + tid * 8);                       \
    gload16(Bb + (size_t)((h) * 128 + 64) * K + (size_t)(kt) * 64,               \
            lds + (d) * DSZ + ASZ + (h) * 8192 + 4096 + tid * 8); } while (0)

    int aoff[MF][2], boff[4][2];
#pragma unroll
    for (int m = 0; m < MF; ++m) {
        int R = wr * (BM / 2) + m * 16 + l15;
#pragma unroll
        for (int ks = 0; ks < 2; ++ks)
            aoff[m][ks] = R * 64 + (((ks * 4 + l16) ^ (R & 7)) * 8);
    }
#pragma unroll
    for (int n = 0; n < 4; ++n) {
        int R = wc * 64 + n * 16 + l15;
#pragma unroll
        for (int ks = 0; ks < 2; ++ks)
            boff[n][ks] = ASZ + R * 64 + (((ks * 4 + l16) ^ (R & 7)) * 8);
    }

    f32x4 acc[MF][4] = {};
    half8 bfr[4][2];
    const int nj = K >> 7;

    STAGE_A(0, 0);
    STAGE_B(0, 0, 0); STAGE_B(0, 1, 0);
    STAGE_B(1, 0, 1); STAGE_B(1, 1, 1);
    VMW(4);
    __builtin_amdgcn_s_barrier();
    __builtin_amdgcn_sched_barrier(0);

#define PH(TT, Q, STAGECODE, VMCODE) do {                                        \
    const int dB_ = (TT) * DSZ;                                                  \
    half8 af_[AQ][2];                                                            \
    if ((Q) == 0) {                                                              \
        _Pragma("unroll") for (int n_ = 0; n_ < 4; ++n_)                         \
        _Pragma("unroll") for (int ks_ = 0; ks_ < 2; ++ks_)                      \
            bfr[n_][ks_] = *(const half8*)(lds + dB_ + boff[n_][ks_]);           \
    }                                                                            \
    _Pragma("unroll") for (int a_ = 0; a_ < AQ; ++a_)                            \
    _Pragma("unroll") for (int ks_ = 0; ks_ < 2; ++ks_)                          \
        af_[a_][ks_] = *(const half8*)(lds + dB_ + aoff[(Q) * AQ + a_][ks_]);    \
    STAGECODE;                                                                   \
    __builtin_amdgcn_s_barrier();                                                \
    asm volatile("s_waitcnt lgkmcnt(0)" ::: "memory");                           \
    __builtin_amdgcn_sched_barrier(0);                                           \
    __builtin_amdgcn_s_setprio(1);                                               \
    _Pragma("unroll") for (int ks_ = 0; ks_ < 2; ++ks_)                          \
    _Pragma("unroll") for (int a_ = 0; a_ < AQ; ++a_)                            \
    _Pragma("unroll") for (int n_ = 0; n_ < 4; ++n_)                             \
        acc[(Q) * AQ + a_][n_] = __builtin_amdgcn_mfma_f32_16x16x32_f16(         \
            af_[a_][ks_], bfr[n_][ks_], acc[(Q) * AQ + a_][n_], 0, 0, 0);        \
    __builtin_amdgcn_s_setprio(0);                                               \
    __builtin_amdgcn_sched_barrier(0);                                           \
    VMCODE;                                                                      \
    __builtin_amdgcn_s_barrier();                                                \
} while (0)

    for (int j = 0; j < nj; ++j) {
        const bool pf = (j + 1 < nj);
        const int t1 = 2 * j + 1, tn0 = 2 * j + 2, tn1 = 2 * j + 3;
        PH(0, 0, { STAGE_A(1, t1); }, {});
        PH(0, 1, { if (pf) STAGE_B(0, 0, tn0); }, {});
        PH(0, 2, { if (pf) STAGE_B(0, 1, tn0); }, {});
        PH(0, 3, {}, { if (pf) { VMW(4); } else { VMW(0); } });
        PH(1, 0, { if (pf) STAGE_A(0, tn0); }, {});
        PH(1, 1, {}, {});
        PH(1, 2, { if (pf) STAGE_B(1, 0, tn1); }, {});
        PH(1, 3, { if (pf) STAGE_B(1, 1, tn1); }, { if (pf) VMW(4); });
    }
#undef PH
#undef STAGE_A
#undef STAGE_B

    // epilogue: two-pass LDS bounce (128 rows/pass), coalesced half8 stores
    const int sel = bn >> 11;
    _Float16* __restrict__ C = sel == 0 ? C0 : sel == 1 ? C1 : sel == 2 ? C2 : C3;
    const int ccol0 = bn & 2047;
    _Float16* bb = lds;
#pragma unroll
    for (int p = 0; p < 2; ++p) {
        if (p) __syncthreads();
        if (wr == p) {
#pragma unroll
            for (int m = 0; m < MF; ++m)
#pragma unroll
                for (int n = 0; n < 4; ++n)
#pragma unroll
                    for (int r = 0; r < 4; ++r)
                        bb[(m * 16 + l16 * 4 + r) * 264 + wc * 64 + n * 16 + l15] =
                            (_Float16)acc[m][n][r];
        }
        __syncthreads();
#pragma unroll
        for (int rep = 0; rep < 8; ++rep) {
            int u = rep * 512 + tid;
            int i = u >> 5, q = u & 31;
            *(half8*)(C + (size_t)(bm + p * 128 + i) * 2048 + ccol0 + q * 8) =
                *(const half8*)(bb + i * 264 + q * 8);
        }
    }
}

// ---------------------------------------------------------------------------
// Occupancy-2 pipelined GEMM (round-8 structure) for the Wo matmul:
// BM=256 x BN=128, BK=32, 8 waves (4M x 2N), 3 LDS buffers, counted vmcnt,
// verified swizzle. Epilogue: two-pass f32 bounce -> float4 stores.
// ---------------------------------------------------------------------------
template <int BM, typename OT>
__global__ __launch_bounds__(512, 4) void gemmp(const _Float16* __restrict__ A,
                                                const _Float16* __restrict__ Bt,
                                                OT* __restrict__ C0, OT* __restrict__ C1,
                                                OT* __restrict__ C2, OT* __restrict__ C3,
                                                int K, int nx, int cpx)
{
    static_assert(BM == 256, "two-pass epilogue assumes BM=256");
    constexpr int BN   = 128;
    constexpr int LPT  = (BM + BN) / 128;
    constexpr int WR   = BM / 4;
    constexpr int MF   = WR / 16;
    constexpr int ASZ  = BM * 32;
    constexpr int DSZ  = (BM + BN) * 32;
    __shared__ alignas(16) char ldsraw[3 * DSZ * 2];
    _Float16* lds = reinterpret_cast<_Float16*>(ldsraw);

    const int tid = threadIdx.x;
    const int lane = tid & 63, w = tid >> 6;
    const int wr = w >> 1, wc = w & 1;
    const int l15 = lane & 15, l16 = lane >> 4;

    const int bid = blockIdx.x;
    const int swz = (bid & 7) * cpx + (bid >> 3);
    const int bm = (swz / nx) * BM, bn = (swz % nx) * BN;

    const _Float16* src[LPT];
    int ldst[LPT];
#pragma unroll
    for (int ld = 0; ld < LPT; ++ld) {
        int F = ld * 512 + tid;
        int R = F >> 2;
        int sc = (F & 3) ^ (((R >> 3) & 1) << 1);
        src[ld] = (R < BM) ? A + (size_t)(bm + R) * K + sc * 8
                           : Bt + (size_t)(bn + R - BM) * K + sc * 8;
        ldst[ld] = F * 8;
    }

    int aoff[MF], boff[4];
#pragma unroll
    for (int m = 0; m < MF; ++m) {
        int R = wr * WR + m * 16 + l15;
        aoff[m] = R * 32 + ((l16 ^ (((R >> 3) & 1) << 1)) * 8);
    }
#pragma unroll
    for (int n = 0; n < 4; ++n) {
        int R = wc * 64 + n * 16 + l15;
        boff[n] = ASZ + R * 32 + ((l16 ^ (((R >> 3) & 1) << 1)) * 8);
    }

    f32x4 acc[MF][4] = {};
    const int nt = K >> 5;

#define STAGE(kt, buf) do { _Pragma("unroll")                                  \
    for (int ld_ = 0; ld_ < LPT; ++ld_)                                        \
        gload16(src[ld_] + (size_t)(kt) * 32, lds + (buf) * DSZ + ldst[ld_]);  \
    } while (0)

    STAGE(0, 0);
    STAGE(1, 1);
    VMW(3);
    __builtin_amdgcn_s_barrier();
    __builtin_amdgcn_sched_barrier(0);

    int cb = 0, nb = 2;
    for (int t = 0; t < nt; ++t) {
        const _Float16* L = lds + cb * DSZ;
        half8 af[MF], bf[4];
#pragma unroll
        for (int m = 0; m < MF; ++m) af[m] = *(const half8*)(L + aoff[m]);
#pragma unroll
        for (int n = 0; n < 4; ++n) bf[n] = *(const half8*)(L + boff[n]);

        const bool pf = (t + 2 < nt);
        if (pf) STAGE(t + 2, nb);

        asm volatile("s_waitcnt lgkmcnt(0)" ::: "memory");
        __builtin_amdgcn_sched_barrier(0);
        __builtin_amdgcn_s_setprio(1);
#pragma unroll
        for (int m = 0; m < MF; ++m)
#pragma unroll
            for (int n = 0; n < 4; ++n)
                acc[m][n] = __builtin_amdgcn_mfma_f32_16x16x32_f16(af[m], bf[n], acc[m][n], 0, 0, 0);
        __builtin_amdgcn_s_setprio(0);
        __builtin_amdgcn_sched_barrier(0);

        if (pf) VMW(3);
        else    VMW(0);
        __builtin_amdgcn_s_barrier();
        __builtin_amdgcn_sched_barrier(0);

        cb = (cb == 2) ? 0 : cb + 1;
        nb = (nb == 2) ? 0 : nb + 1;
    }
#undef STAGE

    // epilogue: two 128-row passes through an LDS bounce, float4/half8 stores
    const int sel = bn >> 11;
    OT* __restrict__ C = sel == 0 ? C0 : sel == 1 ? C1 : sel == 2 ? C2 : C3;
    const int ccol0 = bn & 2047;
    constexpr int VE = 16 / sizeof(OT);
    constexpr int CPR = 128 / VE;
    constexpr int BW = 128 + VE;
    OT* bb = reinterpret_cast<OT*>(ldsraw);
#pragma unroll
    for (int p = 0; p < 2; ++p) {
        if (p) __syncthreads();
        if ((wr >> 1) == p) {
            const int rb = (wr & 1) * 64;
#pragma unroll
            for (int m = 0; m < MF; ++m)
#pragma unroll
                for (int n = 0; n < 4; ++n)
#pragma unroll
                    for (int r = 0; r < 4; ++r)
                        bb[(rb + m * 16 + l16 * 4 + r) * BW + wc * 64 + n * 16 + l15] =
                            (OT)acc[m][n][r];
        }
        __syncthreads();
#pragma unroll
        for (int rep = 0; rep < (128 * CPR) / 512; ++rep) {
            int u = rep * 512 + tid;
            int i = u / CPR, q = u % CPR;
            if constexpr (sizeof(OT) == 2)
                *reinterpret_cast<half8*>(C + (size_t)(bm + p * 128 + i) * 2048 + ccol0 + q * VE) =
                    *reinterpret_cast<const half8*>(bb + i * BW + q * VE);
            else
                *reinterpret_cast<float4*>(C + (size_t)(bm + p * 128 + i) * 2048 + ccol0 + q * VE) =
                    *reinterpret_cast<const float4*>(bb + i * BW + q * VE);
        }
    }
}

// ---------------------------------------------------------------------------
// conv_all: y=0 -> q conv+silu (8ch/thread); y=1 -> v conv; y=2 -> k+norm.
// ---------------------------------------------------------------------------
__global__ __launch_bounds__(256) void conv_all(const _Float16* __restrict__ pq,
                                                const _Float16* __restrict__ pk,
                                                const _Float16* __restrict__ pv,
                                                const float* __restrict__ qw,
                                                const float* __restrict__ qb,
                                                const float* __restrict__ kw,
                                                const float* __restrict__ kb,
                                                const float* __restrict__ vw,
                                                const float* __restrict__ vb,
                                                _Float16* __restrict__ qh,
                                                _Float16* __restrict__ kh,
                                                _Float16* __restrict__ vh)
{
    const int y = blockIdx.y;
    if (y == 2) {
        int lane = threadIdx.x & 63, wv = threadIdx.x >> 6;
        size_t r = (size_t)blockIdx.x * 4 + wv;
        int h = (int)(r & 15);
        size_t gr = r >> 4;
        int t = (int)(gr & (T_ - 1));
        int c0 = h * 128 + lane * 2;

        float a0 = kb[c0], a1 = kb[c0 + 1];
#pragma unroll
        for (int j = 0; j < 4; ++j) {
            int ts = t - 3 + j;
            if (ts >= 0) {
                const _Float16* p = pk + (gr - 3 + j) * DIM_ + c0;
                a0 += (float)p[0] * kw[c0 * 4 + j];
                a1 += (float)p[1] * kw[(c0 + 1) * 4 + j];
            }
        }
        a0 = a0 * sigmoidf_(a0);
        a1 = a1 * sigmoidf_(a1);
        float ss = a0 * a0 + a1 * a1;
#pragma unroll
        for (int off = 1; off < 64; off <<= 1) ss += __shfl_xor(ss, off);
        float sc = 1.0f / fmaxf(sqrtf(ss), 1e-12f);
        kh[gr * DIM_ + c0]     = (_Float16)(a0 * sc);
        kh[gr * DIM_ + c0 + 1] = (_Float16)(a1 * sc);
        return;
    }
    if (blockIdx.x >= 4096) return;
    const int act = (y == 0);
    const _Float16* xin = act ? pq : pv;
    const float* w = act ? qw : vw;
    const float* bias = act ? qb : vb;
    _Float16* yo = act ? qh : vh;

    int idx = blockIdx.x * 256 + threadIdx.x;
    int c8 = (idx & 255) * 8;
    int t = (idx >> 8) & (T_ - 1);
    int b = idx >> 19;
    const size_t rowbase = ((size_t)b * T_ + t) * DIM_ + c8;

    float4 w4[8];
    float accv[8];
#pragma unroll
    for (int u = 0; u < 8; ++u) {
        w4[u] = *(const float4*)(w + (c8 + u) * 4);
        accv[u] = bias[c8 + u];
    }
    const _Float16* xc = xin + rowbase;
#pragma unroll
    for (int j = 0; j < 4; ++j) {
        int ts = t - 3 + j;
        if (ts >= 0) {
            half8 xv = *(const half8*)(xc + (ptrdiff_t)(j - 3) * DIM_);
#pragma unroll
            for (int u = 0; u < 8; ++u)
                accv[u] += (float)xv[u] * ((const float*)&w4[u])[j];
        }
    }
    half8 o;
#pragma unroll
    for (int u = 0; u < 8; ++u) {
        float v = accv[u];
        if (act) v = v * sigmoidf_(v);
        o[u] = (_Float16)v;
    }
    *(half8*)(yo + rowbase) = o;
}

// ---------------------------------------------------------------------------
// R1: per (bh, chunk) U_c = sum_s bet*decay^(63-s) * v_s k_s^T  (128x128 f16)
// ---------------------------------------------------------------------------
__global__ __launch_bounds__(256) void r1_kernel(const _Float16* __restrict__ kh,
                                                 const _Float16* __restrict__ vh,
                                                 const float* __restrict__ A_log,
                                                 const float* __restrict__ beta,
                                                 _Float16* __restrict__ U)
{
    const int c = blockIdx.x & 31, bh = blockIdx.x >> 5;
    const int h = bh & 15, b = bh >> 4;
    const float decay = sigmoidf_(A_log[h]);
    const float bet = sigmoidf_(beta[h]);
    const float ld = logf(decay);

    __shared__ _Float16 sm[2 * 128 * 72];
    __shared__ float pw[64];
    _Float16* kt = sm;
    _Float16* vt = sm + 128 * 72;

    const int tid = threadIdx.x;
    if (tid < 64) pw[tid] = bet * __expf(ld * (float)(63 - tid));
    __syncthreads();

    const size_t base = ((size_t)(b * T_ + c * 64) * H_ + h) * 128;
#pragma unroll
    for (int rep = 0; rep < 4; ++rep) {
        int idx = rep * 256 + tid;
        int s = idx >> 4, dq = idx & 15;
        half8 kv = *(const half8*)(kh + base + (size_t)s * DIM_ + dq * 8);
        half8 vv = *(const half8*)(vh + base + (size_t)s * DIM_ + dq * 8);
        float sc = pw[s];
#pragma unroll
        for (int j = 0; j < 8; ++j) {
            kt[tsw(dq * 8 + j, s)] = kv[j];
            vt[tsw(dq * 8 + j, s)] = (_Float16)(sc * (float)vv[j]);
        }
    }
    __syncthreads();

    const int lane = tid & 63, w = tid >> 6;
    const int l15 = lane & 15, l16 = lane >> 4;
    f32x4 acc[2][8] = {};
#pragma unroll
    for (int ks = 0; ks < 2; ++ks) {
        half8 a0 = *(const half8*)(vt + tswb(w * 32 + l15,      ks * 4 + l16));
        half8 a1 = *(const half8*)(vt + tswb(w * 32 + 16 + l15, ks * 4 + l16));
#pragma unroll
        for (int fj = 0; fj < 8; ++fj) {
            half8 bf = *(const half8*)(kt + tswb(fj * 16 + l15, ks * 4 + l16));
            acc[0][fj] = __builtin_amdgcn_mfma_f32_16x16x32_f16(a0, bf, acc[0][fj], 0, 0, 0);
            acc[1][fj] = __builtin_amdgcn_mfma_f32_16x16x32_f16(a1, bf, acc[1][fj], 0, 0, 0);
        }
    }
    __syncthreads();

    _Float16* buf = sm;
#pragma unroll
    for (int fi = 0; fi < 2; ++fi)
#pragma unroll
        for (int fj = 0; fj < 8; ++fj)
#pragma unroll
            for (int r = 0; r < 4; ++r)
                buf[(w * 32 + fi * 16 + l16 * 4 + r) * 136 + fj * 16 + l15] =
                    (_Float16)acc[fi][fj][r];
    __syncthreads();

    _Float16* Ub = U + (((size_t)blockIdx.x) << 14);
#pragma unroll
    for (int rep = 0; rep < 8; ++rep) {
        int u = rep * 256 + tid;
        int i = u >> 4, jq = u & 15;
        *(half8*)(Ub + i * 128 + jq * 8) = *(const half8*)(buf + i * 136 + jq * 8);
    }
}

// ---------------------------------------------------------------------------
// R2: chunk-boundary state scan, parallel over (bh, 2048-elem slices).
// ---------------------------------------------------------------------------
__global__ __launch_bounds__(256) void r2_kernel(const _Float16* __restrict__ U,
                                                 _Float16* __restrict__ S,
                                                 const float* __restrict__ A_log)
{
    const int blk = blockIdx.x;
    const int bh = blk >> 3, part = blk & 7, h = bh & 15;
    const float decay = sigmoidf_(A_log[h]);
    const float d64 = __expf(64.0f * logf(decay));
    const size_t base = ((size_t)bh << 19) + (size_t)part * 2048 + (size_t)threadIdx.x * 8;
    const half8* Up = (const half8*)(U + base);
    half8* Sp = (half8*)(S + base);

    float st[8] = {0, 0, 0, 0, 0, 0, 0, 0};
    half8 n0 = Up[0];
    half8 n1 = Up[2048];
    for (int c = 0; c < 32; ++c) {
        half8 cur = n0;
        n0 = n1;
        if (c + 2 < 32) n1 = Up[(size_t)(c + 2) * 2048];
        half8 so;
#pragma unroll
        for (int i = 0; i < 8; ++i) {
            so[i] = (_Float16)st[i];
            st[i] = d64 * st[i] + (float)cur[i];
        }
        Sp[(size_t)c * 2048] = so;
    }
}

// ---------------------------------------------------------------------------
// R3: per (bh, chunk): out = mask(QK^T)V + rowscale(Q S^T); gate fused.
// k staged through LDS (coalesced + XOR-chunk swizzle); kbuf reused as bounce.
// ---------------------------------------------------------------------------
__global__ __launch_bounds__(256) void r3_kernel(const _Float16* __restrict__ qh,
                                                 const _Float16* __restrict__ kh,
                                                 const _Float16* __restrict__ vh,
                                                 const _Float16* __restrict__ S,
                                                 const _Float16* __restrict__ pg,
                                                 const float* __restrict__ A_log,
                                                 const float* __restrict__ beta,
                                                 _Float16* __restrict__ gated)
{
    const int c = blockIdx.x & 31, bh = blockIdx.x >> 5;
    const int h = bh & 15, b = bh >> 4;
    const float decay = sigmoidf_(A_log[h]);
    const float bet = sigmoidf_(beta[h]);
    const float ld = logf(decay);

    __shared__ _Float16 vt[128 * 72];       // [n][s] swizzled (tsw)
    __shared__ _Float16 ps[64][72];
    __shared__ _Float16 kbuf[64 * 136];     // k staged; reused as out bounce
    __shared__ float e1[65];

    const int tid = threadIdx.x;
    if (tid < 65) e1[tid] = __expf(ld * (float)tid);

    const size_t base = ((size_t)(b * T_ + c * 64) * H_ + h) * 128;
#pragma unroll
    for (int rep = 0; rep < 4; ++rep) {
        int idx = rep * 256 + tid;          // 1024 units: 64 s x 16 chunks
        int s = idx >> 4, nq = idx & 15;
        half8 vv = *(const half8*)(vh + base + (size_t)s * DIM_ + nq * 8);
        half8 kv = *(const half8*)(kh + base + (size_t)s * DIM_ + nq * 8);
#pragma unroll
        for (int j = 0; j < 8; ++j)
            vt[tsw(nq * 8 + j, s)] = vv[j];
        *(half8*)(kbuf + s * 136 + ((nq ^ (s & 7)) * 8)) = kv;
    }
    __syncthreads();

    const int lane = tid & 63, w = tid >> 6;
    const int l15 = lane & 15, l16 = lane >> 4;

    const _Float16* qrow = qh + base + (size_t)(w * 16 + l15) * DIM_;
    half8 af[4];
#pragma unroll
    for (int kd = 0; kd < 4; ++kd) af[kd] = *(const half8*)(qrow + kd * 32 + l16 * 8);

    f32x4 pacc[4] = {};
#pragma unroll
    for (int sf = 0; sf < 4; ++sf) {
        int s = sf * 16 + l15;
#pragma unroll
        for (int kd = 0; kd < 4; ++kd) {
            half8 bf = *(const half8*)(kbuf + s * 136 + (((kd * 4 + l16) ^ (s & 7)) * 8));
            pacc[sf] = __builtin_amdgcn_mfma_f32_16x16x32_f16(af[kd], bf, pacc[sf], 0, 0, 0);
        }
    }
#pragma unroll
    for (int sf = 0; sf < 4; ++sf)
#pragma unroll
        for (int r = 0; r < 4; ++r) {
            int tl = w * 16 + l16 * 4 + r;
            int s = sf * 16 + l15;
            float f = (s <= tl) ? bet * e1[tl - s] : 0.0f;
            ps[tl][s] = (_Float16)(pacc[sf][r] * f);
        }
    __syncthreads();

    half8 pf[2];
#pragma unroll
    for (int ks = 0; ks < 2; ++ks)
        pf[ks] = *(const half8*)&ps[w * 16 + l15][ks * 32 + l16 * 8];

    f32x4 acc1[8] = {};
    f32x4 acc2[8] = {};
    const _Float16* Sb = S + (((size_t)blockIdx.x) << 14);
#pragma unroll
    for (int nf = 0; nf < 8; ++nf) {
#pragma unroll
        for (int kd = 0; kd < 4; ++kd) {
            half8 bf = *(const half8*)(Sb + (size_t)(nf * 16 + l15) * 128 + kd * 32 + l16 * 8);
            acc1[nf] = __builtin_amdgcn_mfma_f32_16x16x32_f16(af[kd], bf, acc1[nf], 0, 0, 0);
        }
#pragma unroll
        for (int ks = 0; ks < 2; ++ks) {
            half8 bf = *(const half8*)(vt + tswb(nf * 16 + l15, ks * 4 + l16));
            acc2[nf] = __builtin_amdgcn_mfma_f32_16x16x32_f16(pf[ks], bf, acc2[nf], 0, 0, 0);
        }
    }
    // bounce the 64x128 out tile into kbuf (k reads finished pre-ps-barrier)
#pragma unroll
    for (int nf = 0; nf < 8; ++nf)
#pragma unroll
        for (int r = 0; r < 4; ++r) {
            int tl = w * 16 + l16 * 4 + r;
            float o = acc2[nf][r] + e1[tl + 1] * acc1[nf][r];
            kbuf[tl * 136 + nf * 16 + l15] = (_Float16)o;
        }
    __syncthreads();

#pragma unroll
    for (int rep = 0; rep < 4; ++rep) {
        int u = rep * 256 + tid;
        int tl = u >> 4, jq = u & 15;
        size_t row = (size_t)(b * T_ + c * 64 + tl);
        half8 o8 = *(const half8*)(kbuf + tl * 136 + jq * 8);
        half8 g8 = *(const half8*)(pg + row * DIM_ + h * 128 + jq * 8);
        half8 r8;
#pragma unroll
        for (int j = 0; j < 8; ++j)
            r8[j] = (_Float16)((float)o8[j] * sigmoidf_((float)g8[j]));
        *(half8*)(gated + row * DIM_ + h * 128 + jq * 8) = r8;
    }
}

// ---------------------------------------------------------------------------
extern "C" void kernel_launch(void* const* d_in, const int* in_sizes, int n_in,
                              void* d_out, int out_size, void* d_ws, size_t ws_size,
                              hipStream_t stream)
{
    const float* x     = (const float*)d_in[0];
    const float* Wq    = (const float*)d_in[1];
    const float* Wk    = (const float*)d_in[2];
    const float* Wv    = (const float*)d_in[3];
    const float* Wo    = (const float*)d_in[4];
    const float* Wg    = (const float*)d_in[5];
    const float* qw    = (const float*)d_in[6];
    const float* qb    = (const float*)d_in[7];
    const float* kw    = (const float*)d_in[8];
    const float* kb    = (const float*)d_in[9];
    const float* vw    = (const float*)d_in[10];
    const float* vb    = (const float*)d_in[11];
    const float* beta  = (const float*)d_in[12];
    const float* A_log = (const float*)d_in[13];
    float* out = (float*)d_out;

    char* wsb = (char*)d_ws;
    const size_t WT  = (size_t)DIM_ * DIM_ * 2;
    const size_t SZ  = (size_t)B_ * T_ * DIM_;
    const size_t SZH = SZ * 2;

    _Float16* wtq = (_Float16*)(wsb + 0 * WT);    // wtq..wtg contiguous = Bt[8192][2048]
    _Float16* wto = (_Float16*)(wsb + 4 * WT);
    char* pbase = wsb + 5 * WT;
    _Float16* pq = (_Float16*)(pbase + 0 * SZH);
    _Float16* pk = (_Float16*)(pbase + 1 * SZH);
    _Float16* pv = (_Float16*)(pbase + 2 * SZH);
    _Float16* xh = (_Float16*)(pbase + 3 * SZH);
    _Float16* pg = (_Float16*)(pbase + 4 * SZH);
    _Float16* qh = (_Float16*)(pbase + 5 * SZH);
    _Float16* kh = (_Float16*)(pbase + 6 * SZH);
    _Float16* vh = (_Float16*)(pbase + 7 * SZH);
    _Float16* U     = pq;  // 32 MB, spans pq+pk (dead after convs)
    _Float16* Sst   = pv;  // 32 MB, spans pv+xh (dead after conv_v / GEMMs)
    _Float16* gated = pq;  // 16 MB, U dead after r2

    // cvt + 5 weight transposes in one launch
    prep<<<dim3(32, 32, 6), 256, 0, stream>>>(Wq, Wk, Wv, Wg, Wo, wtq, x, xh);

    // fused projections: M=4096, N=8192 (q|k|v|g): 16x32 = 512 tiles of 256^2
    gemm8ph<256><<<512, 512, 0, stream>>>(xh, wtq, pq, pk, pv, pg,
                                          DIM_, 32, 64);

    // q conv / v conv / k conv+norm in one launch
    conv_all<<<dim3(16384, 3), 256, 0, stream>>>(pq, pk, pv,
                                                 qw, qb, kw, kb, vw, vb,
                                                 qh, kh, vh);

    r1_kernel<<<B_ * H_ * 32, 256, 0, stream>>>(kh, vh, A_log, beta, U);
    r2_kernel<<<256, 256, 0, stream>>>(U, Sst, A_log);
    r3_kernel<<<B_ * H_ * 32, 256, 0, stream>>>(qh, kh, vh, Sst, pg, A_log, beta, gated);

    // out = gated @ Wo : M=4096, N=2048 -> 16x16 = 256 tiles of 256x128
    gemmp<256, float><<<256, 512, 0, stream>>>(gated, wto, out, out, out, out,
                                               DIM_, 16, 32);
}